// Round 1
// baseline (1765.596 us; speedup 1.0000x reference)
//
#include <hip/hip_runtime.h>

#define N_NODES 20000
#define N_EDGES 320000
#define N_GRAPH 256

// ------------------------- tiled fp32 GEMM: C = op(A@B + bias) -------------------------
#define BM 64
#define BN 64
#define BK 16

__launch_bounds__(256)
__global__ void gemm_kernel(const float* __restrict__ A, int lda,
                            const float* __restrict__ B, int ldb,
                            float* __restrict__ C, int ldc,
                            const float* __restrict__ bias,
                            int Nr, int K, int M, int do_relu) {
  __shared__ __align__(16) float As[BK][BM];
  __shared__ __align__(16) float Bs[BK][BN];
  const int tid = threadIdx.x;
  const int row0 = blockIdx.y * BM;
  const int col0 = blockIdx.x * BN;
  const int tx = tid & 15, ty = tid >> 4;
  const int ar = tid >> 2, ak = (tid & 3) << 2;   // A-load: row in tile, 4 consecutive k
  const int bk = tid >> 4, bc = (tid & 15) << 2;  // B-load: k row, 4 consecutive cols
  float acc[4][4] = {};

  for (int k0 = 0; k0 < K; k0 += BK) {
    const bool rok = (row0 + ar) < Nr;
    const float* Ap = A + (size_t)(row0 + ar) * lda + k0 + ak;
#pragma unroll
    for (int i = 0; i < 4; ++i) {
      int kk = ak + i;
      As[kk][ar] = (rok && (k0 + kk) < K) ? Ap[i] : 0.f;
    }
    const bool kok = (k0 + bk) < K;
    const float* Bp = B + (size_t)(k0 + bk) * ldb + col0 + bc;
#pragma unroll
    for (int j = 0; j < 4; ++j) {
      Bs[bk][bc + j] = (kok && (col0 + bc + j) < M) ? Bp[j] : 0.f;
    }
    __syncthreads();
#pragma unroll
    for (int kk = 0; kk < BK; ++kk) {
      const float4 av = *(const float4*)&As[kk][ty * 4];
      const float4 bv = *(const float4*)&Bs[kk][tx * 4];
      const float a[4] = {av.x, av.y, av.z, av.w};
      const float b[4] = {bv.x, bv.y, bv.z, bv.w};
#pragma unroll
      for (int i = 0; i < 4; ++i)
#pragma unroll
        for (int j = 0; j < 4; ++j)
          acc[i][j] += a[i] * b[j];
    }
    __syncthreads();
  }
#pragma unroll
  for (int i = 0; i < 4; ++i) {
    int r = row0 + ty * 4 + i;
    if (r >= Nr) continue;
#pragma unroll
    for (int j = 0; j < 4; ++j) {
      int c = col0 + tx * 4 + j;
      if (c >= M) continue;
      float v = acc[i][j];
      if (bias) v += bias[c];
      if (do_relu) v = fmaxf(v, 0.f);
      C[(size_t)r * ldc + c] = v;
    }
  }
}

// ------------------------- graph prep -------------------------
__global__ void hist_kernel(const int* __restrict__ ei, int* __restrict__ cnt, int E) {
  int e = blockIdx.x * blockDim.x + threadIdx.x;
  if (e < E) atomicAdd(&cnt[ei[E + e]], 1);  // dst row of edge_index
}

__global__ void scan_kernel(const int* __restrict__ cnt, int* __restrict__ row_ptr,
                            int* __restrict__ cursor, int n) {
  __shared__ int sh[1024];
  int tid = threadIdx.x;
  int chunk = (n + 1023) >> 10;
  int beg = tid * chunk;
  int end = min(beg + chunk, n);
  int s = 0;
  for (int i = beg; i < end; ++i) s += cnt[i];
  sh[tid] = s;
  __syncthreads();
  for (int off = 1; off < 1024; off <<= 1) {
    int v = (tid >= off) ? sh[tid - off] : 0;
    __syncthreads();
    sh[tid] += v;
    __syncthreads();
  }
  int run = sh[tid] - s;  // exclusive prefix for this chunk
  for (int i = beg; i < end; ++i) {
    row_ptr[i] = run;
    cursor[i] = run;
    run += cnt[i];
  }
  if (tid == 1023) row_ptr[n] = sh[1023];
}

__global__ void dinv_kernel(const int* __restrict__ cnt, float* __restrict__ dinv, int n) {
  int i = blockIdx.x * blockDim.x + threadIdx.x;
  if (i < n) dinv[i] = rsqrtf((float)(cnt[i] + 1));  // deg = indeg + self-loop
}

__global__ void scatter_kernel(const int* __restrict__ ei, int* __restrict__ cursor,
                               int* __restrict__ col_idx, int E) {
  int e = blockIdx.x * blockDim.x + threadIdx.x;
  if (e < E) {
    int d = ei[E + e];
    int p = atomicAdd(&cursor[d], 1);
    col_idx[p] = ei[e];  // src
  }
}

// out[n] = relu( dinv[n] * ( sum_{s in in(n)} dinv[s]*h[s] + dinv[n]*h[n] ) + bias )
__global__ void agg_kernel(const float* __restrict__ h, const int* __restrict__ row_ptr,
                           const int* __restrict__ col_idx, const float* __restrict__ dinv,
                           const float* __restrict__ bias, float* __restrict__ out, int F) {
  int n = blockIdx.x;
  int f0 = threadIdx.x, f1 = f0 + 128, f2 = f0 + 256;
  bool v0 = f0 < F, v1 = f1 < F, v2 = f2 < F;
  float din = dinv[n];
  const float* hn = h + (size_t)n * F;
  float a0 = v0 ? din * hn[f0] : 0.f;
  float a1 = v1 ? din * hn[f1] : 0.f;
  float a2 = v2 ? din * hn[f2] : 0.f;
  int beg = row_ptr[n], end = row_ptr[n + 1];
  for (int e = beg; e < end; ++e) {
    int s = col_idx[e];
    float ds = dinv[s];
    const float* hs = h + (size_t)s * F;
    if (v0) a0 += ds * hs[f0];
    if (v1) a1 += ds * hs[f1];
    if (v2) a2 += ds * hs[f2];
  }
  float* on = out + (size_t)n * F;
  if (v0) on[f0] = fmaxf(din * a0 + bias[f0], 0.f);
  if (v1) on[f1] = fmaxf(din * a1 + bias[f1], 0.f);
  if (v2) on[f2] = fmaxf(din * a2 + bias[f2], 0.f);
}

__global__ void starts_kernel(const int* __restrict__ batch, int* __restrict__ start,
                              int n, int G) {
  int i = blockIdx.x * blockDim.x + threadIdx.x;
  if (i >= n) return;
  if (i == 0) { start[0] = 0; start[G] = n; }
  else if (batch[i] != batch[i - 1]) start[batch[i]] = i;
}

__global__ void pool_kernel(const float* __restrict__ x, const int* __restrict__ start,
                            float* __restrict__ pooled, int F) {
  int g = blockIdx.x;
  int beg = start[g], end = start[g + 1];
  for (int f = threadIdx.x; f < F; f += blockDim.x) {
    float m = 0.f;  // post-ReLU values are >= 0
    for (int nn = beg; nn < end; ++nn) m = fmaxf(m, x[(size_t)nn * F + f]);
    pooled[(size_t)g * F + f] = m;
  }
}

__global__ void rownorm_kernel(const float* __restrict__ cell, float* __restrict__ cv, int F) {
  int g = blockIdx.x;
  __shared__ float red[256];
  int tid = threadIdx.x;
  const float* row = cell + (size_t)g * F;
  float s = 0.f;
  for (int f = tid; f < F; f += 256) { float v = row[f]; s += v * v; }
  red[tid] = s;
  __syncthreads();
  for (int off = 128; off > 0; off >>= 1) {
    if (tid < off) red[tid] += red[tid + off];
    __syncthreads();
  }
  float inv = 1.f / fmaxf(sqrtf(red[0]), 1e-12f);
  float* orow = cv + (size_t)g * F;
  for (int f = tid; f < F; f += 256) orow[f] = row[f] * inv;
}

// ------------------------- launcher -------------------------
extern "C" void kernel_launch(void* const* d_in, const int* in_sizes, int n_in,
                              void* d_out, int out_size, void* d_ws, size_t ws_size,
                              hipStream_t stream) {
  (void)in_sizes; (void)n_in; (void)out_size; (void)ws_size;
  const float* x1  = (const float*)d_in[0];
  const int*   ei1 = (const int*)d_in[1];
  const int*   bt1 = (const int*)d_in[2];
  const float* x2  = (const float*)d_in[3];
  const int*   ei2 = (const int*)d_in[4];
  const int*   bt2 = (const int*)d_in[5];
  const float* cell = (const float*)d_in[6];
  const float* Wc1 = (const float*)d_in[7];  const float* bc1 = (const float*)d_in[8];
  const float* Wc2 = (const float*)d_in[9];  const float* bc2 = (const float*)d_in[10];
  const float* Wc3 = (const float*)d_in[11]; const float* bc3 = (const float*)d_in[12];
  const float* Wg1 = (const float*)d_in[13]; const float* bg1 = (const float*)d_in[14];
  const float* Wg2 = (const float*)d_in[15]; const float* bg2 = (const float*)d_in[16];
  const float* Wr1 = (const float*)d_in[17]; const float* br1 = (const float*)d_in[18];
  const float* Wr2 = (const float*)d_in[19]; const float* br2 = (const float*)d_in[20];
  const float* Wr3 = (const float*)d_in[21]; const float* br3 = (const float*)d_in[22];
  const float* Wf1 = (const float*)d_in[23]; const float* bf1 = (const float*)d_in[24];
  const float* Wf2 = (const float*)d_in[25]; const float* bf2 = (const float*)d_in[26];
  const float* Wf3 = (const float*)d_in[27]; const float* bf3 = (const float*)d_in[28];
  const float* Wo  = (const float*)d_in[29]; const float* bo  = (const float*)d_in[30];
  float* out = (float*)d_out;

  char* ws = (char*)d_ws;
  size_t off = 0;
  auto alloc_f = [&](size_t ne) { float* p = (float*)(ws + off); off += ne * 4; return p; };
  auto alloc_i = [&](size_t ne) { int* p = (int*)(ws + off); off += ne * 4; return p; };
  float* xbuf   = alloc_f((size_t)N_NODES * 312);
  float* hbuf   = alloc_f((size_t)N_NODES * 312);
  float* dinv   = alloc_f(N_NODES);
  float* pooled = alloc_f((size_t)N_GRAPH * 312);
  float* cvbuf  = alloc_f((size_t)N_GRAPH * 954);
  float* gtmp1  = alloc_f((size_t)N_GRAPH * 2048);
  float* gtmp2  = alloc_f((size_t)N_GRAPH * 512);
  float* gtmp3  = alloc_f((size_t)N_GRAPH * 128);
  float* catbuf = alloc_f((size_t)N_GRAPH * 512);
  int* cnt     = alloc_i(N_NODES);
  int* row_ptr = alloc_i(N_NODES + 1);
  int* cursor  = alloc_i(N_NODES);
  int* col_idx = alloc_i(N_EDGES);
  int* start   = alloc_i(N_GRAPH + 1);

  auto gemm = [&](const float* A, int lda, const float* B, int ldb, float* C, int ldc,
                  const float* bias, int Nr, int K, int M, int relu) {
    dim3 grid((M + BN - 1) / BN, (Nr + BM - 1) / BM);
    gemm_kernel<<<grid, 256, 0, stream>>>(A, lda, B, ldb, C, ldc, bias, Nr, K, M, relu);
  };

  for (int b = 0; b < 2; ++b) {
    const float* x  = b ? x2 : x1;
    const int* ei   = b ? ei2 : ei1;
    const int* bat  = b ? bt2 : bt1;
    hipMemsetAsync(cnt, 0, N_NODES * sizeof(int), stream);
    hist_kernel<<<(N_EDGES + 255) / 256, 256, 0, stream>>>(ei, cnt, N_EDGES);
    scan_kernel<<<1, 1024, 0, stream>>>(cnt, row_ptr, cursor, N_NODES);
    dinv_kernel<<<(N_NODES + 255) / 256, 256, 0, stream>>>(cnt, dinv, N_NODES);
    scatter_kernel<<<(N_EDGES + 255) / 256, 256, 0, stream>>>(ei, cursor, col_idx, N_EDGES);

    gemm(x, 78, Wc1, 78, hbuf, 78, nullptr, N_NODES, 78, 78, 0);
    agg_kernel<<<N_NODES, 128, 0, stream>>>(hbuf, row_ptr, col_idx, dinv, bc1, xbuf, 78);
    gemm(xbuf, 78, Wc2, 156, hbuf, 156, nullptr, N_NODES, 78, 156, 0);
    agg_kernel<<<N_NODES, 128, 0, stream>>>(hbuf, row_ptr, col_idx, dinv, bc2, xbuf, 156);
    gemm(xbuf, 156, Wc3, 312, hbuf, 312, nullptr, N_NODES, 156, 312, 0);
    agg_kernel<<<N_NODES, 128, 0, stream>>>(hbuf, row_ptr, col_idx, dinv, bc3, xbuf, 312);

    starts_kernel<<<(N_NODES + 255) / 256, 256, 0, stream>>>(bat, start, N_NODES, N_GRAPH);
    pool_kernel<<<N_GRAPH, 128, 0, stream>>>(xbuf, start, pooled, 312);
    gemm(pooled, 312, Wg1, 156, gtmp1, 156, bg1, N_GRAPH, 312, 156, 1);
    gemm(gtmp1, 156, Wg2, 128, catbuf + b * 128, 512, bg2, N_GRAPH, 156, 128, 0);
  }

  rownorm_kernel<<<N_GRAPH, 256, 0, stream>>>(cell, cvbuf, 954);
  gemm(cvbuf, 954, Wr1, 2048, gtmp1, 2048, br1, N_GRAPH, 954, 2048, 1);
  gemm(gtmp1, 2048, Wr2, 512, gtmp2, 512, br2, N_GRAPH, 2048, 512, 1);
  gemm(gtmp2, 512, Wr3, 256, catbuf + 256, 512, br3, N_GRAPH, 512, 256, 1);

  gemm(catbuf, 512, Wf1, 1024, gtmp1, 1024, bf1, N_GRAPH, 512, 1024, 1);
  gemm(gtmp1, 1024, Wf2, 512, gtmp2, 512, bf2, N_GRAPH, 1024, 512, 1);
  gemm(gtmp2, 512, Wf3, 128, gtmp3, 128, bf3, N_GRAPH, 512, 128, 1);
  gemm(gtmp3, 128, Wo, 2, out, 2, bo, N_GRAPH, 128, 2, 0);
}

// Round 2
// 1034.002 us; speedup vs baseline: 1.7075x; 1.7075x over previous
//
#include <hip/hip_runtime.h>

#define N_NODES 20000
#define N_EDGES 320000
#define N_GRAPH 256

// ------------------------- tiled fp32 GEMM -------------------------
// direct path (gridDim.z==1): C = op(A@B + bias)
// split-K path (gridDim.z>1): C += partial (atomicAdd; C pre-zeroed; bias applied later)
#define BM 64
#define BN 64
#define BK 16
#define BKP 20  // padded leading dim for As (conflict-free, keeps float4 alignment)

__launch_bounds__(256)
__global__ void gemm_kernel(const float* __restrict__ A, int lda,
                            const float* __restrict__ B, int ldb,
                            float* __restrict__ C, int ldc,
                            const float* __restrict__ bias,
                            int Nr, int K, int M, int do_relu, int kchunk) {
  __shared__ __align__(16) float As[BM][BKP];  // [row][k]
  __shared__ __align__(16) float Bs[BK][BN];
  const int tid = threadIdx.x;
  const int row0 = blockIdx.y * BM;
  const int col0 = blockIdx.x * BN;
  const int tx = tid & 15, ty = tid >> 4;
  const int ar = tid >> 2, ak = (tid & 3) << 2;   // A-load: row, 4 consecutive k
  const int bk = tid >> 4, bc = (tid & 15) << 2;  // B-load: k row, 4 consecutive cols
  float acc[4][4] = {};
  const int klo = blockIdx.z * kchunk;
  const int khi = min(klo + kchunk, K);

  for (int k0 = klo; k0 < khi; k0 += BK) {
    // stage A (transposed layout: aligned float4 LDS store, 2-way max conflict)
    float4 av = make_float4(0.f, 0.f, 0.f, 0.f);
    const int kb = k0 + ak;
    if (row0 + ar < Nr) {
      const float* Ap = A + (size_t)(row0 + ar) * lda + kb;
      if (kb + 3 < khi) {
        av.x = Ap[0]; av.y = Ap[1]; av.z = Ap[2]; av.w = Ap[3];
      } else {
        if (kb     < khi) av.x = Ap[0];
        if (kb + 1 < khi) av.y = Ap[1];
        if (kb + 2 < khi) av.z = Ap[2];
        if (kb + 3 < khi) av.w = Ap[3];
      }
    }
    *(float4*)&As[ar][ak] = av;
    // stage B
    float4 bv = make_float4(0.f, 0.f, 0.f, 0.f);
    const int kr = k0 + bk;
    if (kr < khi) {
      const float* Bp = B + (size_t)kr * ldb + col0 + bc;
      if (col0 + bc + 3 < M) {
        bv.x = Bp[0]; bv.y = Bp[1]; bv.z = Bp[2]; bv.w = Bp[3];
      } else {
        if (col0 + bc     < M) bv.x = Bp[0];
        if (col0 + bc + 1 < M) bv.y = Bp[1];
        if (col0 + bc + 2 < M) bv.z = Bp[2];
        if (col0 + bc + 3 < M) bv.w = Bp[3];
      }
    }
    *(float4*)&Bs[bk][bc] = bv;
    __syncthreads();
#pragma unroll
    for (int kk = 0; kk < BK; ++kk) {
      const int r4 = ty * 4;
      const float a0 = As[r4 + 0][kk];
      const float a1 = As[r4 + 1][kk];
      const float a2 = As[r4 + 2][kk];
      const float a3 = As[r4 + 3][kk];
      const float4 b4 = *(const float4*)&Bs[kk][tx * 4];
      acc[0][0] += a0 * b4.x; acc[0][1] += a0 * b4.y; acc[0][2] += a0 * b4.z; acc[0][3] += a0 * b4.w;
      acc[1][0] += a1 * b4.x; acc[1][1] += a1 * b4.y; acc[1][2] += a1 * b4.z; acc[1][3] += a1 * b4.w;
      acc[2][0] += a2 * b4.x; acc[2][1] += a2 * b4.y; acc[2][2] += a2 * b4.z; acc[2][3] += a2 * b4.w;
      acc[3][0] += a3 * b4.x; acc[3][1] += a3 * b4.y; acc[3][2] += a3 * b4.z; acc[3][3] += a3 * b4.w;
    }
    __syncthreads();
  }

  const bool direct = (gridDim.z == 1);
#pragma unroll
  for (int i = 0; i < 4; ++i) {
    const int r = row0 + ty * 4 + i;
    if (r >= Nr) continue;
#pragma unroll
    for (int j = 0; j < 4; ++j) {
      const int c = col0 + tx * 4 + j;
      if (c >= M) continue;
      if (direct) {
        float v = acc[i][j];
        if (bias) v += bias[c];
        if (do_relu) v = fmaxf(v, 0.f);
        C[(size_t)r * ldc + c] = v;
      } else {
        atomicAdd(&C[(size_t)r * ldc + c], acc[i][j]);
      }
    }
  }
}

__global__ void bias_act_kernel(const float* __restrict__ src, float* __restrict__ dst,
                                int ldd, const float* __restrict__ bias,
                                int Nr, int M, int do_relu) {
  int idx = blockIdx.x * blockDim.x + threadIdx.x;
  if (idx >= Nr * M) return;
  int r = idx / M, c = idx - r * M;
  float v = src[idx] + bias[c];
  if (do_relu) v = fmaxf(v, 0.f);
  dst[(size_t)r * ldd + c] = v;
}

// gtmp(512x128): rows 0..255 = branch0, 256..511 = branch1 -> catbuf[256][512] cols 0..255
__global__ void cat_kernel(const float* __restrict__ src, float* __restrict__ dst) {
  int idx = blockIdx.x * blockDim.x + threadIdx.x;
  if (idx >= 512 * 128) return;
  int r = idx >> 7, c = idx & 127;
  dst[(size_t)(r & 255) * 512 + ((r >> 8) << 7) + c] = src[idx];
}

// ------------------------- graph prep -------------------------
__global__ void hist_kernel(const int* __restrict__ ei, int* __restrict__ cnt, int E, int off) {
  int e = blockIdx.x * blockDim.x + threadIdx.x;
  if (e < E) atomicAdd(&cnt[off + ei[E + e]], 1);
}

__global__ void scan_kernel(const int* __restrict__ cnt, int* __restrict__ row_ptr,
                            int* __restrict__ cursor, int n) {
  __shared__ int sh[1024];
  int tid = threadIdx.x;
  int chunk = (n + 1023) >> 10;
  int beg = tid * chunk;
  int end = min(beg + chunk, n);
  int s = 0;
  for (int i = beg; i < end; ++i) s += cnt[i];
  sh[tid] = s;
  __syncthreads();
  for (int off = 1; off < 1024; off <<= 1) {
    int v = (tid >= off) ? sh[tid - off] : 0;
    __syncthreads();
    sh[tid] += v;
    __syncthreads();
  }
  int run = sh[tid] - s;
  for (int i = beg; i < end; ++i) {
    row_ptr[i] = run;
    cursor[i] = run;
    run += cnt[i];
  }
  if (tid == 1023) row_ptr[n] = sh[1023];
}

__global__ void dinv_kernel(const int* __restrict__ cnt, float* __restrict__ dinv, int n) {
  int i = blockIdx.x * blockDim.x + threadIdx.x;
  if (i < n) dinv[i] = rsqrtf((float)(cnt[i] + 1));
}

__global__ void scatter_kernel(const int* __restrict__ ei, int* __restrict__ cursor,
                               int* __restrict__ col_idx, int E, int off) {
  int e = blockIdx.x * blockDim.x + threadIdx.x;
  if (e < E) {
    int d = off + ei[E + e];
    int p = atomicAdd(&cursor[d], 1);
    col_idx[p] = off + ei[e];
  }
}

// ------------------------- normalized aggregation -------------------------
// out[n] = relu( dinv[n]*( sum_s dinv[s]*h[s] + dinv[n]*h[n] ) + bias ), vectorized
__global__ void agg4_kernel(const float* __restrict__ h, const int* __restrict__ row_ptr,
                            const int* __restrict__ col_idx, const float* __restrict__ dinv,
                            const float* __restrict__ bias, float* __restrict__ out, int F) {
  const int n = blockIdx.x;
  const int V = F >> 2;
  const int v = threadIdx.x;
  const bool ok = v < V;
  const float din = dinv[n];
  float4 a = make_float4(0.f, 0.f, 0.f, 0.f);
  if (ok) {
    float4 x = ((const float4*)(h + (size_t)n * F))[v];
    a.x = din * x.x; a.y = din * x.y; a.z = din * x.z; a.w = din * x.w;
  }
  const int beg = row_ptr[n], end = row_ptr[n + 1];
  int s_next = (beg < end) ? col_idx[beg] : 0;
  for (int e = beg; e < end; ++e) {
    const int s = s_next;
    if (e + 1 < end) s_next = col_idx[e + 1];
    const float ds = dinv[s];
    if (ok) {
      float4 x = ((const float4*)(h + (size_t)s * F))[v];
      a.x += ds * x.x; a.y += ds * x.y; a.z += ds * x.z; a.w += ds * x.w;
    }
  }
  if (ok) {
    float4 bb = ((const float4*)bias)[v];
    float4 o;
    o.x = fmaxf(din * a.x + bb.x, 0.f);
    o.y = fmaxf(din * a.y + bb.y, 0.f);
    o.z = fmaxf(din * a.z + bb.z, 0.f);
    o.w = fmaxf(din * a.w + bb.w, 0.f);
    ((float4*)(out + (size_t)n * F))[v] = o;
  }
}

__global__ void agg2_kernel(const float* __restrict__ h, const int* __restrict__ row_ptr,
                            const int* __restrict__ col_idx, const float* __restrict__ dinv,
                            const float* __restrict__ bias, float* __restrict__ out, int F) {
  const int n = blockIdx.x;
  const int V = F >> 1;
  const int v = threadIdx.x;
  const bool ok = v < V;
  const float din = dinv[n];
  float2 a = make_float2(0.f, 0.f);
  if (ok) {
    float2 x = ((const float2*)(h + (size_t)n * F))[v];
    a.x = din * x.x; a.y = din * x.y;
  }
  const int beg = row_ptr[n], end = row_ptr[n + 1];
  int s_next = (beg < end) ? col_idx[beg] : 0;
  for (int e = beg; e < end; ++e) {
    const int s = s_next;
    if (e + 1 < end) s_next = col_idx[e + 1];
    const float ds = dinv[s];
    if (ok) {
      float2 x = ((const float2*)(h + (size_t)s * F))[v];
      a.x += ds * x.x; a.y += ds * x.y;
    }
  }
  if (ok) {
    float2 bb = ((const float2*)bias)[v];
    float2 o;
    o.x = fmaxf(din * a.x + bb.x, 0.f);
    o.y = fmaxf(din * a.y + bb.y, 0.f);
    ((float2*)(out + (size_t)n * F))[v] = o;
  }
}

__global__ void starts_kernel(const int* __restrict__ batch, int* __restrict__ start,
                              int n, int G, int off) {
  int i = blockIdx.x * blockDim.x + threadIdx.x;
  if (i >= n) return;
  if (i == 0) { start[0] = off; start[G] = off + n; }
  else if (batch[i] != batch[i - 1]) start[batch[i]] = off + i;
}

__global__ void pool_kernel(const float* __restrict__ x, const int* __restrict__ start,
                            float* __restrict__ pooled, int F) {
  int g = blockIdx.x;
  int beg = start[g], end = start[g + 1];
  for (int f = threadIdx.x; f < F; f += blockDim.x) {
    float m = 0.f;  // post-ReLU inputs are >= 0
    for (int nn = beg; nn < end; ++nn) m = fmaxf(m, x[(size_t)nn * F + f]);
    pooled[(size_t)g * F + f] = m;
  }
}

__global__ void rownorm_kernel(const float* __restrict__ cell, float* __restrict__ cv, int F) {
  int g = blockIdx.x;
  __shared__ float red[256];
  int tid = threadIdx.x;
  const float* row = cell + (size_t)g * F;
  float s = 0.f;
  for (int f = tid; f < F; f += 256) { float v = row[f]; s += v * v; }
  red[tid] = s;
  __syncthreads();
  for (int off = 128; off > 0; off >>= 1) {
    if (tid < off) red[tid] += red[tid + off];
    __syncthreads();
  }
  float inv = 1.f / fmaxf(sqrtf(red[0]), 1e-12f);
  float* orow = cv + (size_t)g * F;
  for (int f = tid; f < F; f += 256) orow[f] = row[f] * inv;
}

// ------------------------- launcher -------------------------
extern "C" void kernel_launch(void* const* d_in, const int* in_sizes, int n_in,
                              void* d_out, int out_size, void* d_ws, size_t ws_size,
                              hipStream_t stream) {
  (void)in_sizes; (void)n_in; (void)out_size;
  const float* x1  = (const float*)d_in[0];
  const int*   ei1 = (const int*)d_in[1];
  const int*   bt1 = (const int*)d_in[2];
  const float* x2  = (const float*)d_in[3];
  const int*   ei2 = (const int*)d_in[4];
  const int*   bt2 = (const int*)d_in[5];
  const float* cell = (const float*)d_in[6];
  const float* Wc1 = (const float*)d_in[7];  const float* bc1 = (const float*)d_in[8];
  const float* Wc2 = (const float*)d_in[9];  const float* bc2 = (const float*)d_in[10];
  const float* Wc3 = (const float*)d_in[11]; const float* bc3 = (const float*)d_in[12];
  const float* Wg1 = (const float*)d_in[13]; const float* bg1 = (const float*)d_in[14];
  const float* Wg2 = (const float*)d_in[15]; const float* bg2 = (const float*)d_in[16];
  const float* Wr1 = (const float*)d_in[17]; const float* br1 = (const float*)d_in[18];
  const float* Wr2 = (const float*)d_in[19]; const float* br2 = (const float*)d_in[20];
  const float* Wr3 = (const float*)d_in[21]; const float* br3 = (const float*)d_in[22];
  const float* Wf1 = (const float*)d_in[23]; const float* bf1 = (const float*)d_in[24];
  const float* Wf2 = (const float*)d_in[25]; const float* bf2 = (const float*)d_in[26];
  const float* Wf3 = (const float*)d_in[27]; const float* bf3 = (const float*)d_in[28];
  const float* Wo  = (const float*)d_in[29]; const float* bo  = (const float*)d_in[30];
  float* out = (float*)d_out;

  const bool batched = ws_size >= (size_t)115 * 1024 * 1024;
  const int NN = batched ? 2 * N_NODES : N_NODES;
  const int NE = batched ? 2 * N_EDGES : N_EDGES;
  const int PR = batched ? 2 * N_GRAPH : N_GRAPH;  // pooled rows

  char* ws = (char*)d_ws;
  size_t off = 0;
  auto alloc_f = [&](size_t ne) { float* p = (float*)(ws + off); off += ne * 4; return p; };
  auto alloc_i = [&](size_t ne) { int* p = (int*)(ws + off); off += ne * 4; return p; };
  float* xbuf   = alloc_f((size_t)NN * 312);
  float* hbuf   = alloc_f((size_t)NN * 312);
  float* dinv   = alloc_f(NN);
  float* pooled = alloc_f((size_t)PR * 312);
  float* cvbuf  = alloc_f((size_t)N_GRAPH * 954);
  float* gtmp1  = alloc_f((size_t)N_GRAPH * 2048);
  float* gtmp2  = alloc_f((size_t)N_GRAPH * 512);
  float* gtmp3  = alloc_f((size_t)N_GRAPH * 256);
  float* catbuf = alloc_f((size_t)N_GRAPH * 512);
  int* cnt     = alloc_i(NN);
  int* row_ptr = alloc_i(NN + 1);
  int* cursor  = alloc_i(NN);
  int* col_idx = alloc_i(NE);
  int* start1  = alloc_i(N_GRAPH + 1);
  int* start2  = alloc_i(N_GRAPH + 1);

  auto gemm = [&](const float* A, int lda, const float* B, int ldb, float* C, int ldc,
                  const float* bias, int Nr, int K, int M, int relu) {
    dim3 grid((M + BN - 1) / BN, (Nr + BM - 1) / BM, 1);
    gemm_kernel<<<grid, 256, 0, stream>>>(A, lda, B, ldb, C, ldc, bias, Nr, K, M, relu, K);
  };
  // split-K MLP layer: zero, accumulate, bias+act (Nr = 256 always)
  auto splitk = [&](const float* A, int lda, const float* B, int M_, int K_, int S,
                    float* acc, const float* bias, float* dst, int ldd, int relu) {
    int kchunk = (((K_ + S - 1) / S) + BK - 1) / BK * BK;
    hipMemsetAsync(acc, 0, (size_t)N_GRAPH * M_ * 4, stream);
    dim3 grid((M_ + BN - 1) / BN, (N_GRAPH + BM - 1) / BM, S);
    gemm_kernel<<<grid, 256, 0, stream>>>(A, lda, B, M_, acc, M_, nullptr, N_GRAPH, K_, M_, 0, kchunk);
    int tot = N_GRAPH * M_;
    bias_act_kernel<<<(tot + 255) / 256, 256, 0, stream>>>(acc, dst, ldd, bias, N_GRAPH, M_, relu);
  };

  if (batched) {
    // build one CSR over both graphs (branch1 node ids offset by N_NODES)
    hipMemsetAsync(cnt, 0, NN * sizeof(int), stream);
    hist_kernel<<<(N_EDGES + 255) / 256, 256, 0, stream>>>(ei1, cnt, N_EDGES, 0);
    hist_kernel<<<(N_EDGES + 255) / 256, 256, 0, stream>>>(ei2, cnt, N_EDGES, N_NODES);
    scan_kernel<<<1, 1024, 0, stream>>>(cnt, row_ptr, cursor, NN);
    dinv_kernel<<<(NN + 255) / 256, 256, 0, stream>>>(cnt, dinv, NN);
    scatter_kernel<<<(N_EDGES + 255) / 256, 256, 0, stream>>>(ei1, cursor, col_idx, N_EDGES, 0);
    scatter_kernel<<<(N_EDGES + 255) / 256, 256, 0, stream>>>(ei2, cursor, col_idx, N_EDGES, N_NODES);
    // xcat = [x1; x2]
    hipMemcpyAsync(xbuf, x1, (size_t)N_NODES * 78 * 4, hipMemcpyDeviceToDevice, stream);
    hipMemcpyAsync(xbuf + (size_t)N_NODES * 78, x2, (size_t)N_NODES * 78 * 4,
                   hipMemcpyDeviceToDevice, stream);

    gemm(xbuf, 78, Wc1, 78, hbuf, 78, nullptr, NN, 78, 78, 0);
    agg2_kernel<<<NN, 64, 0, stream>>>(hbuf, row_ptr, col_idx, dinv, bc1, xbuf, 78);
    gemm(xbuf, 78, Wc2, 156, hbuf, 156, nullptr, NN, 78, 156, 0);
    agg4_kernel<<<NN, 64, 0, stream>>>(hbuf, row_ptr, col_idx, dinv, bc2, xbuf, 156);
    gemm(xbuf, 156, Wc3, 312, hbuf, 312, nullptr, NN, 156, 312, 0);
    agg4_kernel<<<NN, 128, 0, stream>>>(hbuf, row_ptr, col_idx, dinv, bc3, xbuf, 312);

    starts_kernel<<<(N_NODES + 255) / 256, 256, 0, stream>>>(bt1, start1, N_NODES, N_GRAPH, 0);
    starts_kernel<<<(N_NODES + 255) / 256, 256, 0, stream>>>(bt2, start2, N_NODES, N_GRAPH, N_NODES);
    pool_kernel<<<N_GRAPH, 128, 0, stream>>>(xbuf, start1, pooled, 312);
    pool_kernel<<<N_GRAPH, 128, 0, stream>>>(xbuf, start2, pooled + (size_t)N_GRAPH * 312, 312);
    // drug head, both branches at once (512 rows)
    gemm(pooled, 312, Wg1, 156, gtmp1, 156, bg1, 2 * N_GRAPH, 312, 156, 1);
    gemm(gtmp1, 156, Wg2, 128, gtmp2, 128, bg2, 2 * N_GRAPH, 156, 128, 0);
    cat_kernel<<<(512 * 128 + 255) / 256, 256, 0, stream>>>(gtmp2, catbuf);
  } else {
    for (int b = 0; b < 2; ++b) {
      const float* x = b ? x2 : x1;
      const int* ei  = b ? ei2 : ei1;
      const int* bat = b ? bt2 : bt1;
      hipMemsetAsync(cnt, 0, NN * sizeof(int), stream);
      hist_kernel<<<(N_EDGES + 255) / 256, 256, 0, stream>>>(ei, cnt, N_EDGES, 0);
      scan_kernel<<<1, 1024, 0, stream>>>(cnt, row_ptr, cursor, NN);
      dinv_kernel<<<(NN + 255) / 256, 256, 0, stream>>>(cnt, dinv, NN);
      scatter_kernel<<<(N_EDGES + 255) / 256, 256, 0, stream>>>(ei, cursor, col_idx, N_EDGES, 0);

      gemm(x, 78, Wc1, 78, hbuf, 78, nullptr, NN, 78, 78, 0);
      agg2_kernel<<<NN, 64, 0, stream>>>(hbuf, row_ptr, col_idx, dinv, bc1, xbuf, 78);
      gemm(xbuf, 78, Wc2, 156, hbuf, 156, nullptr, NN, 78, 156, 0);
      agg4_kernel<<<NN, 64, 0, stream>>>(hbuf, row_ptr, col_idx, dinv, bc2, xbuf, 156);
      gemm(xbuf, 156, Wc3, 312, hbuf, 312, nullptr, NN, 156, 312, 0);
      agg4_kernel<<<NN, 128, 0, stream>>>(hbuf, row_ptr, col_idx, dinv, bc3, xbuf, 312);

      starts_kernel<<<(N_NODES + 255) / 256, 256, 0, stream>>>(bat, start1, N_NODES, N_GRAPH, 0);
      pool_kernel<<<N_GRAPH, 128, 0, stream>>>(xbuf, start1, pooled, 312);
      gemm(pooled, 312, Wg1, 156, gtmp1, 156, bg1, N_GRAPH, 312, 156, 1);
      gemm(gtmp1, 156, Wg2, 128, catbuf + b * 128, 512, bg2, N_GRAPH, 156, 128, 0);
    }
  }

  // cell branch + head MLP (all 256-row deep-K layers via split-K)
  rownorm_kernel<<<N_GRAPH, 256, 0, stream>>>(cell, cvbuf, 954);
  splitk(cvbuf, 954, Wr1, 2048, 954, 4,  gtmp1, br1, gtmp1, 2048, 1);
  splitk(gtmp1, 2048, Wr2, 512, 2048, 16, gtmp2, br2, gtmp2, 512, 1);
  splitk(gtmp2, 512, Wr3, 256, 512, 8,   gtmp3, br3, catbuf + 256, 512, 1);
  splitk(catbuf, 512, Wf1, 1024, 512, 8, gtmp1, bf1, gtmp1, 1024, 1);
  splitk(gtmp1, 1024, Wf2, 512, 1024, 16, gtmp2, bf2, gtmp2, 512, 1);
  splitk(gtmp2, 512, Wf3, 128, 512, 16,  gtmp3, bf3, gtmp3, 128, 1);
  gemm(gtmp3, 128, Wo, 2, out, 2, bo, N_GRAPH, 128, 2, 0);
}

// Round 3
// 958.927 us; speedup vs baseline: 1.8412x; 1.0783x over previous
//
#include <hip/hip_runtime.h>

#define N_NODES 20000
#define N_EDGES 320000
#define N_GRAPH 256

// ------------------------- templated tiled fp32 GEMM -------------------------
// direct (gridDim.z==1): C = op(A@B + bias); split-K (z>1): atomicAdd partials.
// A-tile staged k-major (As[k][row]) so compute reads are float4 on both operands.
template<int BM, int BN, int TM, int TN>
__launch_bounds__(256)
__global__ void gemm_t(const float* __restrict__ A, int lda,
                       const float* __restrict__ B, int ldb,
                       float* __restrict__ C, int ldc,
                       const float* __restrict__ bias,
                       int Nr, int K, int M, int do_relu, int kchunk) {
  constexpr int BK = 16;
  constexpr int LDA = BM + 4;  // pad keeps 16B alignment of rows, breaks conflicts
  __shared__ __align__(16) float As[BK][LDA];
  __shared__ __align__(16) float Bs[BK][BN];
  const int tid = threadIdx.x;
  const int row0 = blockIdx.y * BM, col0 = blockIdx.x * BN;
  constexpr int NX = BN / TN;
  const int tx = tid % NX, ty = tid / NX;
  float acc[TM][TN] = {};
  const int klo = blockIdx.z * kchunk;
  const int khi = min(klo + kchunk, K);

  for (int k0 = klo; k0 < khi; k0 += BK) {
    // stage A: BM rows x BK k, transposed store (scalar loads: lda arbitrary)
    constexpr int A4 = BM * BK / 4;
#pragma unroll
    for (int f = 0; f < A4; f += 256) {
      const int s = f + tid;
      const int row = s >> 2;          // BK/4 = 4 float4-slots per row
      const int kq = (s & 3) << 2;
      float4 av = make_float4(0.f, 0.f, 0.f, 0.f);
      const int gr = row0 + row, gk = k0 + kq;
      if (gr < Nr) {
        const float* Ap = A + (size_t)gr * lda + gk;
        if (gk + 3 < khi) { av.x = Ap[0]; av.y = Ap[1]; av.z = Ap[2]; av.w = Ap[3]; }
        else {
          if (gk     < khi) av.x = Ap[0];
          if (gk + 1 < khi) av.y = Ap[1];
          if (gk + 2 < khi) av.z = Ap[2];
        }
      }
      As[kq    ][row] = av.x;
      As[kq + 1][row] = av.y;
      As[kq + 2][row] = av.z;
      As[kq + 3][row] = av.w;
    }
    // stage B: BK x BN
    constexpr int B4 = BK * BN / 4;
#pragma unroll
    for (int f = 0; f < B4; f += 256) {
      const int s = f + tid;
      const int kr = s / (BN / 4);
      const int c  = (s % (BN / 4)) << 2;
      float4 bv = make_float4(0.f, 0.f, 0.f, 0.f);
      const int gk = k0 + kr, gc = col0 + c;
      if (gk < khi) {
        const float* Bp = B + (size_t)gk * ldb + gc;
        if (gc + 3 < M) { bv.x = Bp[0]; bv.y = Bp[1]; bv.z = Bp[2]; bv.w = Bp[3]; }
        else {
          if (gc     < M) bv.x = Bp[0];
          if (gc + 1 < M) bv.y = Bp[1];
          if (gc + 2 < M) bv.z = Bp[2];
        }
      }
      *(float4*)&Bs[kr][c] = bv;
    }
    __syncthreads();
#pragma unroll
    for (int kk = 0; kk < BK; ++kk) {
      float ar[TM], br[TN];
#pragma unroll
      for (int i = 0; i < TM; i += 4)
        *(float4*)&ar[i] = *(const float4*)&As[kk][ty * TM + i];
#pragma unroll
      for (int j = 0; j < TN; j += 4)
        *(float4*)&br[j] = *(const float4*)&Bs[kk][tx * TN + j];
#pragma unroll
      for (int i = 0; i < TM; ++i)
#pragma unroll
        for (int j = 0; j < TN; ++j)
          acc[i][j] += ar[i] * br[j];
    }
    __syncthreads();
  }

  const bool direct = (gridDim.z == 1);
#pragma unroll
  for (int i = 0; i < TM; ++i) {
    const int r = row0 + ty * TM + i;
    if (r >= Nr) continue;
    float* Crow = C + (size_t)r * ldc;
#pragma unroll
    for (int j4 = 0; j4 < TN; j4 += 4) {
      const int c = col0 + tx * TN + j4;
      if (direct) {
        if (c + 3 < M) {
          float4 v;
          v.x = acc[i][j4 + 0]; v.y = acc[i][j4 + 1];
          v.z = acc[i][j4 + 2]; v.w = acc[i][j4 + 3];
          if (bias) {
            v.x += bias[c]; v.y += bias[c + 1]; v.z += bias[c + 2]; v.w += bias[c + 3];
          }
          if (do_relu) {
            v.x = fmaxf(v.x, 0.f); v.y = fmaxf(v.y, 0.f);
            v.z = fmaxf(v.z, 0.f); v.w = fmaxf(v.w, 0.f);
          }
          *(float4*)&Crow[c] = v;
        } else {
#pragma unroll
          for (int j = 0; j < 4; ++j) {
            if (c + j >= M) continue;
            float v = acc[i][j4 + j];
            if (bias) v += bias[c + j];
            if (do_relu) v = fmaxf(v, 0.f);
            Crow[c + j] = v;
          }
        }
      } else {
#pragma unroll
        for (int j = 0; j < 4; ++j) {
          if (c + j < M) atomicAdd(&Crow[c + j], acc[i][j4 + j]);
        }
      }
    }
  }
}

__global__ void bias_act_kernel(const float* __restrict__ src, float* __restrict__ dst,
                                int ldd, const float* __restrict__ bias,
                                int Nr, int M, int do_relu) {
  int idx = blockIdx.x * blockDim.x + threadIdx.x;
  if (idx >= Nr * M) return;
  int r = idx / M, c = idx - r * M;
  float v = src[idx] + bias[c];
  if (do_relu) v = fmaxf(v, 0.f);
  dst[(size_t)r * ldd + c] = v;
}

// src(512x128): rows 0..255 branch0, 256..511 branch1 -> dst[256][512] cols 0..255
__global__ void cat_kernel(const float* __restrict__ src, float* __restrict__ dst) {
  int idx = blockIdx.x * blockDim.x + threadIdx.x;
  if (idx >= 512 * 128) return;
  int r = idx >> 7, c = idx & 127;
  dst[(size_t)(r & 255) * 512 + ((r >> 8) << 7) + c] = src[idx];
}

// ------------------------- graph prep (both branches in one launch) -------------------------
__global__ void hist2_kernel(const int* __restrict__ e1, const int* __restrict__ e2,
                             int* __restrict__ cnt, int E, int npass) {
  int e = blockIdx.x * blockDim.x + threadIdx.x;
  if (e < E) atomicAdd(&cnt[e1[E + e]], 1);
  else if (e < npass * E) atomicAdd(&cnt[N_NODES + e2[E + e - E]], 1);
}

__global__ void scan_kernel(const int* __restrict__ cnt, int* __restrict__ row_ptr,
                            int* __restrict__ cursor, float* __restrict__ dinv, int n) {
  __shared__ int sh[1024];
  int tid = threadIdx.x;
  int chunk = (n + 1023) >> 10;
  int beg = tid * chunk;
  int end = min(beg + chunk, n);
  int s = 0;
  for (int i = beg; i < end; ++i) s += cnt[i];
  sh[tid] = s;
  __syncthreads();
  for (int off = 1; off < 1024; off <<= 1) {
    int v = (tid >= off) ? sh[tid - off] : 0;
    __syncthreads();
    sh[tid] += v;
    __syncthreads();
  }
  int run = sh[tid] - s;
  for (int i = beg; i < end; ++i) {
    int ci = cnt[i];
    row_ptr[i] = run;
    cursor[i] = run;
    dinv[i] = rsqrtf((float)(ci + 1));
    run += ci;
  }
  if (tid == 1023) row_ptr[n] = sh[1023];
}

__global__ void scatter2_kernel(const int* __restrict__ e1, const int* __restrict__ e2,
                                int* __restrict__ cursor, int* __restrict__ col_idx,
                                int E, int npass) {
  int e = blockIdx.x * blockDim.x + threadIdx.x;
  if (e < E) {
    int p = atomicAdd(&cursor[e1[E + e]], 1);
    col_idx[p] = e1[e];
  } else if (e < npass * E) {
    int j = e - E;
    int p = atomicAdd(&cursor[N_NODES + e2[E + j]], 1);
    col_idx[p] = N_NODES + e2[j];
  }
}

// ------------------------- pure normalized aggregation: out = D^-1/2 (A+I) D^-1/2 x ----------
__global__ void aggf4_kernel(const float* __restrict__ h, const int* __restrict__ row_ptr,
                             const int* __restrict__ col_idx, const float* __restrict__ dinv,
                             float* __restrict__ out, int F) {
  const int n = blockIdx.x;
  const int v = threadIdx.x;
  const bool ok = v < (F >> 2);
  const float din = dinv[n];
  float4 a = make_float4(0.f, 0.f, 0.f, 0.f);
  if (ok) {
    float4 x = ((const float4*)(h + (size_t)n * F))[v];
    a.x = din * x.x; a.y = din * x.y; a.z = din * x.z; a.w = din * x.w;
  }
  const int beg = row_ptr[n], end = row_ptr[n + 1];
  int s_next = (beg < end) ? col_idx[beg] : 0;
  for (int e = beg; e < end; ++e) {
    const int s = s_next;
    if (e + 1 < end) s_next = col_idx[e + 1];
    const float ds = dinv[s];
    if (ok) {
      float4 x = ((const float4*)(h + (size_t)s * F))[v];
      a.x += ds * x.x; a.y += ds * x.y; a.z += ds * x.z; a.w += ds * x.w;
    }
  }
  if (ok) {
    float4 o;
    o.x = din * a.x; o.y = din * a.y; o.z = din * a.z; o.w = din * a.w;
    ((float4*)(out + (size_t)n * F))[v] = o;
  }
}

__global__ void aggf2_kernel(const float* __restrict__ h, const int* __restrict__ row_ptr,
                             const int* __restrict__ col_idx, const float* __restrict__ dinv,
                             float* __restrict__ out, int F) {
  const int n = blockIdx.x;
  const int v = threadIdx.x;
  const bool ok = v < (F >> 1);
  const float din = dinv[n];
  float2 a = make_float2(0.f, 0.f);
  if (ok) {
    float2 x = ((const float2*)(h + (size_t)n * F))[v];
    a.x = din * x.x; a.y = din * x.y;
  }
  const int beg = row_ptr[n], end = row_ptr[n + 1];
  int s_next = (beg < end) ? col_idx[beg] : 0;
  for (int e = beg; e < end; ++e) {
    const int s = s_next;
    if (e + 1 < end) s_next = col_idx[e + 1];
    const float ds = dinv[s];
    if (ok) {
      float2 x = ((const float2*)(h + (size_t)s * F))[v];
      a.x += ds * x.x; a.y += ds * x.y;
    }
  }
  if (ok) {
    float2 o;
    o.x = din * a.x; o.y = din * a.y;
    ((float2*)(out + (size_t)n * F))[v] = o;
  }
}

__global__ void starts2_kernel(const int* __restrict__ b1, const int* __restrict__ b2,
                               int* __restrict__ s1, int* __restrict__ s2, int n, int npass) {
  int i = blockIdx.x * blockDim.x + threadIdx.x;
  if (i < n) {
    if (i == 0) { s1[0] = 0; s1[N_GRAPH] = n; }
    else if (b1[i] != b1[i - 1]) s1[b1[i]] = i;
  } else if (i < npass * n) {
    int j = i - n;
    if (j == 0) { s2[0] = n; s2[N_GRAPH] = 2 * n; }
    else if (b2[j] != b2[j - 1]) s2[b2[j]] = n + j;
  }
}

__global__ void pool_kernel(const float* __restrict__ x, const int* __restrict__ s1,
                            const int* __restrict__ s2, float* __restrict__ pooled,
                            int F, int pool_base) {
  int g = blockIdx.x;
  const int* st = (g < N_GRAPH) ? s1 : s2;
  int gi = g & (N_GRAPH - 1);
  int beg = st[gi], end = st[gi + 1];
  for (int f = threadIdx.x; f < F; f += blockDim.x) {
    float m = 0.f;  // post-ReLU inputs >= 0
    for (int nn = beg; nn < end; ++nn) m = fmaxf(m, x[(size_t)nn * F + f]);
    pooled[(size_t)(pool_base + g) * F + f] = m;
  }
}

__global__ void rownorm_kernel(const float* __restrict__ cell, float* __restrict__ cv, int F) {
  int g = blockIdx.x;
  __shared__ float red[256];
  int tid = threadIdx.x;
  const float* row = cell + (size_t)g * F;
  float s = 0.f;
  for (int f = tid; f < F; f += 256) { float v = row[f]; s += v * v; }
  red[tid] = s;
  __syncthreads();
  for (int off = 128; off > 0; off >>= 1) {
    if (tid < off) red[tid] += red[tid + off];
    __syncthreads();
  }
  float inv = 1.f / fmaxf(sqrtf(red[0]), 1e-12f);
  float* orow = cv + (size_t)g * F;
  for (int f = tid; f < F; f += 256) orow[f] = row[f] * inv;
}

// ------------------------- launcher -------------------------
extern "C" void kernel_launch(void* const* d_in, const int* in_sizes, int n_in,
                              void* d_out, int out_size, void* d_ws, size_t ws_size,
                              hipStream_t stream) {
  (void)in_sizes; (void)n_in; (void)out_size;
  const float* x1  = (const float*)d_in[0];
  const int*   ei1 = (const int*)d_in[1];
  const int*   bt1 = (const int*)d_in[2];
  const float* x2  = (const float*)d_in[3];
  const int*   ei2 = (const int*)d_in[4];
  const int*   bt2 = (const int*)d_in[5];
  const float* cell = (const float*)d_in[6];
  const float* Wc1 = (const float*)d_in[7];  const float* bc1 = (const float*)d_in[8];
  const float* Wc2 = (const float*)d_in[9];  const float* bc2 = (const float*)d_in[10];
  const float* Wc3 = (const float*)d_in[11]; const float* bc3 = (const float*)d_in[12];
  const float* Wg1 = (const float*)d_in[13]; const float* bg1 = (const float*)d_in[14];
  const float* Wg2 = (const float*)d_in[15]; const float* bg2 = (const float*)d_in[16];
  const float* Wr1 = (const float*)d_in[17]; const float* br1 = (const float*)d_in[18];
  const float* Wr2 = (const float*)d_in[19]; const float* br2 = (const float*)d_in[20];
  const float* Wr3 = (const float*)d_in[21]; const float* br3 = (const float*)d_in[22];
  const float* Wf1 = (const float*)d_in[23]; const float* bf1 = (const float*)d_in[24];
  const float* Wf2 = (const float*)d_in[25]; const float* bf2 = (const float*)d_in[26];
  const float* Wf3 = (const float*)d_in[27]; const float* bf3 = (const float*)d_in[28];
  const float* Wo  = (const float*)d_in[29]; const float* bo  = (const float*)d_in[30];
  float* out = (float*)d_out;

  const bool batched = ws_size >= (size_t)95 * 1024 * 1024;
  const int NPASS = batched ? 2 : 1;
  const int NN = NPASS * N_NODES;

  char* ws = (char*)d_ws;
  size_t off = 0;
  auto alloc_f = [&](size_t ne) { float* p = (float*)(ws + off); off += ne * 4; return p; };
  auto alloc_i = [&](size_t ne) { int* p = (int*)(ws + off); off += ne * 4; return p; };
  float* xbuf   = alloc_f((size_t)NN * 312);   // layer activations (widest: 312)
  float* abuf   = alloc_f((size_t)NN * 156);   // aggregated input (widest: 156)
  float* dinv   = alloc_f(NN);
  float* pooled = alloc_f((size_t)512 * 312);
  float* cvbuf  = alloc_f((size_t)N_GRAPH * 954);
  float* gtmp1  = alloc_f((size_t)512 * 2048);
  float* gtmp2  = alloc_f((size_t)512 * 512);
  float* gtmp3  = alloc_f((size_t)N_GRAPH * 256);
  float* catbuf = alloc_f((size_t)N_GRAPH * 512);
  int* cnt     = alloc_i(NN);
  int* row_ptr = alloc_i(NN + 1);
  int* cursor  = alloc_i(NN);
  int* col_idx = alloc_i(NPASS * N_EDGES);
  int* start1  = alloc_i(N_GRAPH + 1);
  int* start2  = alloc_i(N_GRAPH + 1);

  auto gemm_big = [&](const float* A, int lda, const float* B, int ldb, float* C, int ldc,
                      const float* bias, int Nr, int K, int M, int relu) {
    dim3 grid((M + 127) / 128, (Nr + 127) / 128, 1);
    gemm_t<128, 128, 8, 8><<<grid, 256, 0, stream>>>(A, lda, B, ldb, C, ldc, bias, Nr, K, M, relu, K);
  };
  auto gemm_med = [&](const float* A, int lda, const float* B, int ldb, float* C, int ldc,
                      const float* bias, int Nr, int K, int M, int relu) {
    dim3 grid((M + 63) / 64, (Nr + 127) / 128, 1);
    gemm_t<128, 64, 8, 4><<<grid, 256, 0, stream>>>(A, lda, B, ldb, C, ldc, bias, Nr, K, M, relu, K);
  };
  auto gemm_small = [&](const float* A, int lda, const float* B, int ldb, float* C, int ldc,
                        const float* bias, int Nr, int K, int M, int relu) {
    dim3 grid((M + 63) / 64, (Nr + 63) / 64, 1);
    gemm_t<64, 64, 4, 4><<<grid, 256, 0, stream>>>(A, lda, B, ldb, C, ldc, bias, Nr, K, M, relu, K);
  };
  // split-K MLP layer (Nr = 256): zero, atomic accumulate, bias+act
  auto splitk = [&](const float* A, int lda, const float* B, int M_, int K_, int S,
                    float* acc, const float* bias, float* dst, int ldd, int relu) {
    int kchunk = (((K_ + S - 1) / S) + 15) / 16 * 16;
    hipMemsetAsync(acc, 0, (size_t)N_GRAPH * M_ * 4, stream);
    dim3 grid((M_ + 63) / 64, (N_GRAPH + 63) / 64, S);
    gemm_t<64, 64, 4, 4><<<grid, 256, 0, stream>>>(A, lda, B, M_, acc, M_, nullptr,
                                                   N_GRAPH, K_, M_, 0, kchunk);
    int tot = N_GRAPH * M_;
    bias_act_kernel<<<(tot + 255) / 256, 256, 0, stream>>>(acc, dst, ldd, bias, N_GRAPH, M_, relu);
  };

  auto drug_pass = [&](const float* xa, const float* xb, const int* eia, const int* eib,
                       const int* bta, const int* btb, int npass, int pool_base) {
    const int nn = npass * N_NODES;
    const int te = npass * N_EDGES;
    hipMemsetAsync(cnt, 0, nn * sizeof(int), stream);
    hist2_kernel<<<(te + 255) / 256, 256, 0, stream>>>(eia, eib, cnt, N_EDGES, npass);
    scan_kernel<<<1, 1024, 0, stream>>>(cnt, row_ptr, cursor, dinv, nn);
    scatter2_kernel<<<(te + 255) / 256, 256, 0, stream>>>(eia, eib, cursor, col_idx, N_EDGES, npass);
    hipMemcpyAsync(xbuf, xa, (size_t)N_NODES * 78 * 4, hipMemcpyDeviceToDevice, stream);
    if (npass == 2)
      hipMemcpyAsync(xbuf + (size_t)N_NODES * 78, xb, (size_t)N_NODES * 78 * 4,
                     hipMemcpyDeviceToDevice, stream);
    // layer 1: agg(78) -> GEMM 78->78 (+bias,relu)
    aggf2_kernel<<<nn, 64, 0, stream>>>(xbuf, row_ptr, col_idx, dinv, abuf, 78);
    gemm_med(abuf, 78, Wc1, 78, xbuf, 78, bc1, nn, 78, 78, 1);
    // layer 2: agg(78) -> GEMM 78->156
    aggf2_kernel<<<nn, 64, 0, stream>>>(xbuf, row_ptr, col_idx, dinv, abuf, 78);
    gemm_med(abuf, 78, Wc2, 156, xbuf, 156, bc2, nn, 78, 156, 1);
    // layer 3: agg(156) -> GEMM 156->312
    aggf4_kernel<<<nn, 64, 0, stream>>>(xbuf, row_ptr, col_idx, dinv, abuf, 156);
    gemm_big(abuf, 156, Wc3, 312, xbuf, 312, bc3, nn, 156, 312, 1);
    // pool
    starts2_kernel<<<(nn + 255) / 256, 256, 0, stream>>>(bta, btb, start1, start2, N_NODES, npass);
    pool_kernel<<<npass * N_GRAPH, 128, 0, stream>>>(xbuf, start1, start2, pooled, 312, pool_base);
  };

  if (batched) {
    drug_pass(x1, x2, ei1, ei2, bt1, bt2, 2, 0);
  } else {
    drug_pass(x1, x1, ei1, ei1, bt1, bt1, 1, 0);
    drug_pass(x2, x2, ei2, ei2, bt2, bt2, 1, N_GRAPH);
  }

  // drug head on both branches at once (512 rows; shared weights)
  gemm_med(pooled, 312, Wg1, 156, gtmp1, 156, bg1, 2 * N_GRAPH, 312, 156, 1);
  gemm_med(gtmp1, 156, Wg2, 128, gtmp2, 128, bg2, 2 * N_GRAPH, 156, 128, 0);
  cat_kernel<<<(512 * 128 + 255) / 256, 256, 0, stream>>>(gtmp2, catbuf);

  // cell branch + head MLP (256-row deep-K layers via split-K)
  rownorm_kernel<<<N_GRAPH, 256, 0, stream>>>(cell, cvbuf, 954);
  splitk(cvbuf, 954, Wr1, 2048, 954, 4,   gtmp1, br1, gtmp1, 2048, 1);
  splitk(gtmp1, 2048, Wr2, 512, 2048, 16, gtmp2, br2, gtmp2, 512, 1);
  splitk(gtmp2, 512, Wr3, 256, 512, 8,    gtmp3, br3, catbuf + 256, 512, 1);
  splitk(catbuf, 512, Wf1, 1024, 512, 8,  gtmp1, bf1, gtmp1, 1024, 1);
  splitk(gtmp1, 1024, Wf2, 512, 1024, 16, gtmp2, bf2, gtmp2, 512, 1);
  splitk(gtmp2, 512, Wf3, 128, 512, 16,   gtmp3, bf3, gtmp3, 128, 1);
  gemm_small(gtmp3, 128, Wo, 2, out, 2, bo, N_GRAPH, 128, 2, 0);
}

// Round 4
// 769.933 us; speedup vs baseline: 2.2932x; 1.2455x over previous
//
#include <hip/hip_runtime.h>

#define N_NODES 20000
#define N_EDGES 320000
#define N_GRAPH 256

// ------------------------- templated tiled fp32 GEMM -------------------------
// zstride==0: direct C = op(A@B + bias). zstride>0 (split-K): block z plain-stores
// its partial to C + z*zstride (summed later by bias_sum_kernel).
// A-tile staged k-major; B-fragment split in two stride-4 groups (no 4-way bank conflict).
// Register double-buffer: prefetch tile k+1 into VGPRs while computing tile k.
template<int BM, int BN, int TM, int TN>
__launch_bounds__(256)
__global__ void gemm_t(const float* __restrict__ A, int lda,
                       const float* __restrict__ B, int ldb,
                       float* __restrict__ C, int ldc, int zstride,
                       const float* __restrict__ bias,
                       int Nr, int K, int M, int do_relu, int kchunk) {
  constexpr int BK = 16;
  constexpr int LDA = BM + 4;
  __shared__ __align__(16) float As[BK][LDA];
  __shared__ __align__(16) float Bs[BK][BN];
  const int tid = threadIdx.x;
  const int row0 = blockIdx.y * BM, col0 = blockIdx.x * BN;
  constexpr int NX = BN / TN;
  const int tx = tid % NX, ty = tid / NX;
  float acc[TM][TN] = {};
  const int klo = blockIdx.z * kchunk;
  const int khi = min(klo + kchunk, K);

  constexpr int AIT = BM * BK / 4 / 256;
  constexpr int BIT = BK * BN / 4 / 256;
  float4 pa[AIT], pb[BIT];

  auto load_tile = [&](int k0) {
#pragma unroll
    for (int it = 0; it < AIT; ++it) {
      const int s = it * 256 + tid;
      const int row = s >> 2, kq = (s & 3) << 2;
      float4 av = make_float4(0.f, 0.f, 0.f, 0.f);
      const int gr = row0 + row, gk = k0 + kq;
      if (gr < Nr) {
        const float* Ap = A + (size_t)gr * lda + gk;
        if (gk + 3 < khi) { av.x = Ap[0]; av.y = Ap[1]; av.z = Ap[2]; av.w = Ap[3]; }
        else {
          if (gk     < khi) av.x = Ap[0];
          if (gk + 1 < khi) av.y = Ap[1];
          if (gk + 2 < khi) av.z = Ap[2];
        }
      }
      pa[it] = av;
    }
#pragma unroll
    for (int it = 0; it < BIT; ++it) {
      const int s = it * 256 + tid;
      const int kr = s / (BN / 4), c = (s % (BN / 4)) << 2;
      float4 bv = make_float4(0.f, 0.f, 0.f, 0.f);
      const int gk = k0 + kr, gc = col0 + c;
      if (gk < khi) {
        const float* Bp = B + (size_t)gk * ldb + gc;
        if (gc + 3 < M) { bv.x = Bp[0]; bv.y = Bp[1]; bv.z = Bp[2]; bv.w = Bp[3]; }
        else {
          if (gc     < M) bv.x = Bp[0];
          if (gc + 1 < M) bv.y = Bp[1];
          if (gc + 2 < M) bv.z = Bp[2];
        }
      }
      pb[it] = bv;
    }
  };

  load_tile(klo);
  for (int k0 = klo; k0 < khi; k0 += BK) {
    // commit prefetched tile to LDS
#pragma unroll
    for (int it = 0; it < AIT; ++it) {
      const int s = it * 256 + tid;
      const int row = s >> 2, kq = (s & 3) << 2;
      As[kq    ][row] = pa[it].x;
      As[kq + 1][row] = pa[it].y;
      As[kq + 2][row] = pa[it].z;
      As[kq + 3][row] = pa[it].w;
    }
#pragma unroll
    for (int it = 0; it < BIT; ++it) {
      const int s = it * 256 + tid;
      const int kr = s / (BN / 4), c = (s % (BN / 4)) << 2;
      *(float4*)&Bs[kr][c] = pb[it];
    }
    __syncthreads();
    if (k0 + BK < khi) load_tile(k0 + BK);  // overlap next-tile fetch with compute
#pragma unroll
    for (int kk = 0; kk < BK; ++kk) {
      float ar[TM], br[TN];
#pragma unroll
      for (int i = 0; i < TM; i += 4)
        *(float4*)&ar[i] = *(const float4*)&As[kk][ty * TM + i];
      if constexpr (TN == 8) {
        *(float4*)&br[0] = *(const float4*)&Bs[kk][tx * 4];
        *(float4*)&br[4] = *(const float4*)&Bs[kk][BN / 2 + tx * 4];
      } else {
        *(float4*)&br[0] = *(const float4*)&Bs[kk][tx * TN];
      }
#pragma unroll
      for (int i = 0; i < TM; ++i)
#pragma unroll
        for (int j = 0; j < TN; ++j)
          acc[i][j] += ar[i] * br[j];
    }
    __syncthreads();
  }

  float* Cz = C + (size_t)blockIdx.z * zstride;
#pragma unroll
  for (int i = 0; i < TM; ++i) {
    const int r = row0 + ty * TM + i;
    if (r >= Nr) continue;
    float* Crow = Cz + (size_t)r * ldc;
#pragma unroll
    for (int g = 0; g < TN / 4; ++g) {
      const int c = col0 + (TN == 8 ? g * (BN / 2) : 0) + tx * 4;
      if (c + 3 < M) {
        float4 v;
        v.x = acc[i][g * 4 + 0]; v.y = acc[i][g * 4 + 1];
        v.z = acc[i][g * 4 + 2]; v.w = acc[i][g * 4 + 3];
        if (bias) { v.x += bias[c]; v.y += bias[c + 1]; v.z += bias[c + 2]; v.w += bias[c + 3]; }
        if (do_relu) {
          v.x = fmaxf(v.x, 0.f); v.y = fmaxf(v.y, 0.f);
          v.z = fmaxf(v.z, 0.f); v.w = fmaxf(v.w, 0.f);
        }
        *(float4*)&Crow[c] = v;
      } else {
#pragma unroll
        for (int j = 0; j < 4; ++j) {
          if (c + j >= M) continue;
          float v = acc[i][g * 4 + j];
          if (bias) v += bias[c + j];
          if (do_relu) v = fmaxf(v, 0.f);
          Crow[c + j] = v;
        }
      }
    }
  }
}

// sum Sz split-K partials + bias (+relu), write with ldd
__global__ void bias_sum_kernel(const float* __restrict__ src, int zs, int Sz,
                                float* __restrict__ dst, int ldd,
                                const float* __restrict__ bias,
                                int Nr, int M, int do_relu) {
  int idx = blockIdx.x * blockDim.x + threadIdx.x;
  if (idx >= Nr * M) return;
  int r = idx / M, c = idx - r * M;
  float v = bias[c];
  for (int z = 0; z < Sz; ++z) v += src[idx + (size_t)z * zs];
  if (do_relu) v = fmaxf(v, 0.f);
  dst[(size_t)r * ldd + c] = v;
}

// src(512x128): rows 0..255 branch0, 256..511 branch1 -> dst[256][512] cols 0..255
__global__ void cat_kernel(const float* __restrict__ src, float* __restrict__ dst) {
  int idx = blockIdx.x * blockDim.x + threadIdx.x;
  if (idx >= 512 * 128) return;
  int r = idx >> 7, c = idx & 127;
  dst[(size_t)(r & 255) * 512 + ((r >> 8) << 7) + c] = src[idx];
}

// ------------------------- graph prep -------------------------
__global__ void hist2_kernel(const int* __restrict__ e1, const int* __restrict__ e2,
                             int* __restrict__ cnt, int E, int npass) {
  int e = blockIdx.x * blockDim.x + threadIdx.x;
  if (e < E) atomicAdd(&cnt[e1[E + e]], 1);
  else if (e < npass * E) atomicAdd(&cnt[N_NODES + e2[E + e - E]], 1);
}

__global__ void scan_kernel(const int* __restrict__ cnt, int* __restrict__ row_ptr,
                            int* __restrict__ cursor, float* __restrict__ dinv, int n) {
  __shared__ int sh[1024];
  int tid = threadIdx.x;
  int chunk = (n + 1023) >> 10;
  int beg = tid * chunk;
  int end = min(beg + chunk, n);
  int s = 0;
  for (int i = beg; i < end; ++i) s += cnt[i];
  sh[tid] = s;
  __syncthreads();
  for (int off = 1; off < 1024; off <<= 1) {
    int v = (tid >= off) ? sh[tid - off] : 0;
    __syncthreads();
    sh[tid] += v;
    __syncthreads();
  }
  int run = sh[tid] - s;
  for (int i = beg; i < end; ++i) {
    int ci = cnt[i];
    row_ptr[i] = run;
    cursor[i] = run;
    dinv[i] = rsqrtf((float)(ci + 1));
    run += ci;
  }
  if (tid == 1023) row_ptr[n] = sh[1023];
}

__global__ void scatter2_kernel(const int* __restrict__ e1, const int* __restrict__ e2,
                                int* __restrict__ cursor, int* __restrict__ col_idx,
                                int E, int npass) {
  int e = blockIdx.x * blockDim.x + threadIdx.x;
  if (e < E) {
    int p = atomicAdd(&cursor[e1[E + e]], 1);
    col_idx[p] = e1[e];
  } else if (e < npass * E) {
    int j = e - E;
    int p = atomicAdd(&cursor[N_NODES + e2[E + j]], 1);
    col_idx[p] = N_NODES + e2[j];
  }
}

// ------------------------- normalized aggregation: out = D^-1/2 (A+I) D^-1/2 x ---------
// dual-source: node s reads h (s < nsplit) or h2 (s - nsplit); edge-unrolled by 2.
__global__ void aggf2_kernel(const float* __restrict__ h, const float* __restrict__ h2,
                             int nsplit, const int* __restrict__ row_ptr,
                             const int* __restrict__ col_idx, const float* __restrict__ dinv,
                             float* __restrict__ out, int F) {
  const int n = blockIdx.x;
  const int v = threadIdx.x;
  const bool ok = v < (F >> 1);
  const float din = dinv[n];
  auto rowp = [&](int s) -> const float2* {
    const float* base = (s < nsplit) ? h + (size_t)s * F : h2 + (size_t)(s - nsplit) * F;
    return (const float2*)base;
  };
  float2 a = make_float2(0.f, 0.f);
  if (ok) { float2 x = rowp(n)[v]; a.x = din * x.x; a.y = din * x.y; }
  const int beg = row_ptr[n], end = row_ptr[n + 1];
  int e = beg;
  for (; e + 1 < end; e += 2) {
    int s0 = col_idx[e], s1 = col_idx[e + 1];
    float d0 = dinv[s0], d1 = dinv[s1];
    if (ok) {
      float2 x0 = rowp(s0)[v], x1 = rowp(s1)[v];
      a.x += d0 * x0.x + d1 * x1.x;
      a.y += d0 * x0.y + d1 * x1.y;
    }
  }
  if (e < end) {
    int s0 = col_idx[e];
    float d0 = dinv[s0];
    if (ok) { float2 x0 = rowp(s0)[v]; a.x += d0 * x0.x; a.y += d0 * x0.y; }
  }
  if (ok) {
    float2 o; o.x = din * a.x; o.y = din * a.y;
    ((float2*)(out + (size_t)n * F))[v] = o;
  }
}

__global__ void aggf4_kernel(const float* __restrict__ h, const int* __restrict__ row_ptr,
                             const int* __restrict__ col_idx, const float* __restrict__ dinv,
                             float* __restrict__ out, int F) {
  const int n = blockIdx.x;
  const int v = threadIdx.x;
  const bool ok = v < (F >> 2);
  const float din = dinv[n];
  const float4* hv = (const float4*)h;
  const int vs = F >> 2;
  float4 a = make_float4(0.f, 0.f, 0.f, 0.f);
  if (ok) {
    float4 x = hv[(size_t)n * vs + v];
    a.x = din * x.x; a.y = din * x.y; a.z = din * x.z; a.w = din * x.w;
  }
  const int beg = row_ptr[n], end = row_ptr[n + 1];
  int e = beg;
  for (; e + 1 < end; e += 2) {
    int s0 = col_idx[e], s1 = col_idx[e + 1];
    float d0 = dinv[s0], d1 = dinv[s1];
    if (ok) {
      float4 x0 = hv[(size_t)s0 * vs + v], x1 = hv[(size_t)s1 * vs + v];
      a.x += d0 * x0.x + d1 * x1.x;
      a.y += d0 * x0.y + d1 * x1.y;
      a.z += d0 * x0.z + d1 * x1.z;
      a.w += d0 * x0.w + d1 * x1.w;
    }
  }
  if (e < end) {
    int s0 = col_idx[e];
    float d0 = dinv[s0];
    if (ok) {
      float4 x0 = hv[(size_t)s0 * vs + v];
      a.x += d0 * x0.x; a.y += d0 * x0.y; a.z += d0 * x0.z; a.w += d0 * x0.w;
    }
  }
  if (ok) {
    float4 o;
    o.x = din * a.x; o.y = din * a.y; o.z = din * a.z; o.w = din * a.w;
    ((float4*)(out + (size_t)n * F))[v] = o;
  }
}

__global__ void starts2_kernel(const int* __restrict__ b1, const int* __restrict__ b2,
                               int* __restrict__ s1, int* __restrict__ s2, int n, int npass) {
  int i = blockIdx.x * blockDim.x + threadIdx.x;
  if (i < n) {
    if (i == 0) { s1[0] = 0; s1[N_GRAPH] = n; }
    else if (b1[i] != b1[i - 1]) s1[b1[i]] = i;
  } else if (i < npass * n) {
    int j = i - n;
    if (j == 0) { s2[0] = n; s2[N_GRAPH] = 2 * n; }
    else if (b2[j] != b2[j - 1]) s2[b2[j]] = n + j;
  }
}

__global__ void pool_kernel(const float* __restrict__ x, const int* __restrict__ s1,
                            const int* __restrict__ s2, float* __restrict__ pooled,
                            int F, int pool_base) {
  int g = blockIdx.x;
  const int* st = (g < N_GRAPH) ? s1 : s2;
  int gi = g & (N_GRAPH - 1);
  int beg = st[gi], end = st[gi + 1];
  for (int f = threadIdx.x; f < F; f += blockDim.x) {
    float m = 0.f;  // post-ReLU inputs >= 0
    for (int nn = beg; nn < end; ++nn) m = fmaxf(m, x[(size_t)nn * F + f]);
    pooled[(size_t)(pool_base + g) * F + f] = m;
  }
}

__global__ void rownorm_kernel(const float* __restrict__ cell, float* __restrict__ cv, int F) {
  int g = blockIdx.x;
  __shared__ float red[256];
  int tid = threadIdx.x;
  const float* row = cell + (size_t)g * F;
  float s = 0.f;
  for (int f = tid; f < F; f += 256) { float v = row[f]; s += v * v; }
  red[tid] = s;
  __syncthreads();
  for (int off = 128; off > 0; off >>= 1) {
    if (tid < off) red[tid] += red[tid + off];
    __syncthreads();
  }
  float inv = 1.f / fmaxf(sqrtf(red[0]), 1e-12f);
  float* orow = cv + (size_t)g * F;
  for (int f = tid; f < F; f += 256) orow[f] = row[f] * inv;
}

// ------------------------- launcher -------------------------
extern "C" void kernel_launch(void* const* d_in, const int* in_sizes, int n_in,
                              void* d_out, int out_size, void* d_ws, size_t ws_size,
                              hipStream_t stream) {
  (void)in_sizes; (void)n_in; (void)out_size;
  const float* x1  = (const float*)d_in[0];
  const int*   ei1 = (const int*)d_in[1];
  const int*   bt1 = (const int*)d_in[2];
  const float* x2  = (const float*)d_in[3];
  const int*   ei2 = (const int*)d_in[4];
  const int*   bt2 = (const int*)d_in[5];
  const float* cell = (const float*)d_in[6];
  const float* Wc1 = (const float*)d_in[7];  const float* bc1 = (const float*)d_in[8];
  const float* Wc2 = (const float*)d_in[9];  const float* bc2 = (const float*)d_in[10];
  const float* Wc3 = (const float*)d_in[11]; const float* bc3 = (const float*)d_in[12];
  const float* Wg1 = (const float*)d_in[13]; const float* bg1 = (const float*)d_in[14];
  const float* Wg2 = (const float*)d_in[15]; const float* bg2 = (const float*)d_in[16];
  const float* Wr1 = (const float*)d_in[17]; const float* br1 = (const float*)d_in[18];
  const float* Wr2 = (const float*)d_in[19]; const float* br2 = (const float*)d_in[20];
  const float* Wr3 = (const float*)d_in[21]; const float* br3 = (const float*)d_in[22];
  const float* Wf1 = (const float*)d_in[23]; const float* bf1 = (const float*)d_in[24];
  const float* Wf2 = (const float*)d_in[25]; const float* bf2 = (const float*)d_in[26];
  const float* Wf3 = (const float*)d_in[27]; const float* bf3 = (const float*)d_in[28];
  const float* Wo  = (const float*)d_in[29]; const float* bo  = (const float*)d_in[30];
  float* out = (float*)d_out;

  const bool batched = ws_size >= (size_t)95 * 1024 * 1024;
  const int NPASS = batched ? 2 : 1;
  const int NN = NPASS * N_NODES;

  char* ws = (char*)d_ws;
  size_t off = 0;
  auto alloc_f = [&](size_t ne) { float* p = (float*)(ws + off); off += ne * 4; return p; };
  auto alloc_i = [&](size_t ne) { int* p = (int*)(ws + off); off += ne * 4; return p; };
  float* xbuf   = alloc_f((size_t)NN * 312);   // activations; also aliased as split-K acc
  float* abuf   = alloc_f((size_t)NN * 156);
  float* dinv   = alloc_f(NN);
  float* pooled = alloc_f((size_t)512 * 312);
  float* cvbuf  = alloc_f((size_t)N_GRAPH * 954);
  float* gtmp1  = alloc_f((size_t)512 * 2048);
  float* gtmp2  = alloc_f((size_t)512 * 512);
  float* gtmp3  = alloc_f((size_t)N_GRAPH * 256);
  float* catbuf = alloc_f((size_t)N_GRAPH * 512);
  int* cnt     = alloc_i(NN);
  int* row_ptr = alloc_i(NN + 1);
  int* cursor  = alloc_i(NN);
  int* col_idx = alloc_i(NPASS * N_EDGES);
  int* start1  = alloc_i(N_GRAPH + 1);
  int* start2  = alloc_i(N_GRAPH + 1);
  float* accb  = xbuf;  // split-K partials (MLP runs after pooling; xbuf free then)

  auto gemm_big = [&](const float* A, int lda, const float* B, int ldb, float* C, int ldc,
                      const float* bias, int Nr, int K, int M, int relu) {
    dim3 grid((M + 127) / 128, (Nr + 127) / 128, 1);
    gemm_t<128, 128, 8, 8><<<grid, 256, 0, stream>>>(A, lda, B, ldb, C, ldc, 0, bias,
                                                     Nr, K, M, relu, K);
  };
  auto gemm_med = [&](const float* A, int lda, const float* B, int ldb, float* C, int ldc,
                      const float* bias, int Nr, int K, int M, int relu) {
    dim3 grid((M + 63) / 64, (Nr + 127) / 128, 1);
    gemm_t<128, 64, 8, 4><<<grid, 256, 0, stream>>>(A, lda, B, ldb, C, ldc, 0, bias,
                                                    Nr, K, M, relu, K);
  };
  auto gemm_small = [&](const float* A, int lda, const float* B, int ldb, float* C, int ldc,
                        const float* bias, int Nr, int K, int M, int relu) {
    dim3 grid((M + 63) / 64, (Nr + 63) / 64, 1);
    gemm_t<64, 64, 4, 4><<<grid, 256, 0, stream>>>(A, lda, B, ldb, C, ldc, 0, bias,
                                                   Nr, K, M, relu, K);
  };
  // split-K MLP layer (Nr = 256): partial stores per z-slice + summing bias/act pass
  auto splitk = [&](const float* A, int lda, const float* B, int M_, int K_, int S,
                    const float* bias, float* dst, int ldd, int relu) {
    int kchunk = (((K_ + S - 1) / S) + 15) / 16 * 16;
    int Sz = (K_ + kchunk - 1) / kchunk;
    dim3 grid((M_ + 63) / 64, (N_GRAPH + 63) / 64, Sz);
    gemm_t<64, 64, 4, 4><<<grid, 256, 0, stream>>>(A, lda, B, M_, accb, M_, N_GRAPH * M_,
                                                   nullptr, N_GRAPH, K_, M_, 0, kchunk);
    int tot = N_GRAPH * M_;
    bias_sum_kernel<<<(tot + 255) / 256, 256, 0, stream>>>(accb, N_GRAPH * M_, Sz, dst, ldd,
                                                           bias, N_GRAPH, M_, relu);
  };

  auto drug_pass = [&](const float* xa, const float* xb, const int* eia, const int* eib,
                       const int* bta, const int* btb, int npass, int pool_base) {
    const int nn = npass * N_NODES;
    const int te = npass * N_EDGES;
    hipMemsetAsync(cnt, 0, nn * sizeof(int), stream);
    hist2_kernel<<<(te + 255) / 256, 256, 0, stream>>>(eia, eib, cnt, N_EDGES, npass);
    scan_kernel<<<1, 1024, 0, stream>>>(cnt, row_ptr, cursor, dinv, nn);
    scatter2_kernel<<<(te + 255) / 256, 256, 0, stream>>>(eia, eib, cursor, col_idx, N_EDGES, npass);
    // layer 1: agg(78, dual-source virtual concat) -> GEMM 78->78 (+bias,relu)
    aggf2_kernel<<<nn, 64, 0, stream>>>(xa, xb, N_NODES, row_ptr, col_idx, dinv, abuf, 78);
    gemm_med(abuf, 78, Wc1, 78, xbuf, 78, bc1, nn, 78, 78, 1);
    // layer 2: agg(78) -> GEMM 78->156
    aggf2_kernel<<<nn, 64, 0, stream>>>(xbuf, xbuf, nn, row_ptr, col_idx, dinv, abuf, 78);
    gemm_med(abuf, 78, Wc2, 156, xbuf, 156, bc2, nn, 78, 156, 1);
    // layer 3: agg(156) -> GEMM 156->312
    aggf4_kernel<<<nn, 64, 0, stream>>>(xbuf, row_ptr, col_idx, dinv, abuf, 156);
    gemm_big(abuf, 156, Wc3, 312, xbuf, 312, bc3, nn, 156, 312, 1);
    // pool
    starts2_kernel<<<(nn + 255) / 256, 256, 0, stream>>>(bta, btb, start1, start2, N_NODES, npass);
    pool_kernel<<<npass * N_GRAPH, 128, 0, stream>>>(xbuf, start1, start2, pooled, 312, pool_base);
  };

  if (batched) {
    drug_pass(x1, x2, ei1, ei2, bt1, bt2, 2, 0);
  } else {
    drug_pass(x1, x1, ei1, ei1, bt1, bt1, 1, 0);
    drug_pass(x2, x2, ei2, ei2, bt2, bt2, 1, N_GRAPH);
  }

  // drug head on both branches at once (512 rows; shared weights)
  gemm_med(pooled, 312, Wg1, 156, gtmp1, 156, bg1, 2 * N_GRAPH, 312, 156, 1);
  gemm_med(gtmp1, 156, Wg2, 128, gtmp2, 128, bg2, 2 * N_GRAPH, 156, 128, 0);
  cat_kernel<<<(512 * 128 + 255) / 256, 256, 0, stream>>>(gtmp2, catbuf);

  // cell branch + head MLP (256-row deep-K layers via split-K)
  rownorm_kernel<<<N_GRAPH, 256, 0, stream>>>(cell, cvbuf, 954);
  splitk(cvbuf, 954, Wr1, 2048, 954, 4,   br1, gtmp1, 2048, 1);
  splitk(gtmp1, 2048, Wr2, 512, 2048, 16, br2, gtmp2, 512, 1);
  splitk(gtmp2, 512, Wr3, 256, 512, 8,    br3, catbuf + 256, 512, 1);
  splitk(catbuf, 512, Wf1, 1024, 512, 8,  bf1, gtmp1, 1024, 1);
  splitk(gtmp1, 1024, Wf2, 512, 1024, 16, bf2, gtmp2, 512, 1);
  splitk(gtmp2, 512, Wf3, 128, 512, 16,   bf3, gtmp3, 128, 1);
  gemm_small(gtmp3, 128, Wo, 2, out, 2, bo, N_GRAPH, 128, 2, 0);
}

// Round 5
// 683.566 us; speedup vs baseline: 2.5829x; 1.1263x over previous
//
#include <hip/hip_runtime.h>

#define N_NODES 20000
#define N_EDGES 320000
#define N_GRAPH 256

// ------------------------- templated tiled fp32 GEMM -------------------------
// zstride==0: direct C = op(A@B + bias). zstride>0 (split-K): block z plain-stores
// its partial to C + z*zstride (summed later by bias_sum_kernel).
// A-tile staged k-major; B-fragment split in two stride-4 groups (no 4-way bank conflict).
// Register double-buffer: prefetch tile k+1 into VGPRs while computing tile k.
template<int BM, int BN, int TM, int TN>
__launch_bounds__(256)
__global__ void gemm_t(const float* __restrict__ A, int lda,
                       const float* __restrict__ B, int ldb,
                       float* __restrict__ C, int ldc, int zstride,
                       const float* __restrict__ bias,
                       int Nr, int K, int M, int do_relu, int kchunk) {
  constexpr int BK = 16;
  constexpr int LDA = BM + 4;
  __shared__ __align__(16) float As[BK][LDA];
  __shared__ __align__(16) float Bs[BK][BN];
  const int tid = threadIdx.x;
  const int row0 = blockIdx.y * BM, col0 = blockIdx.x * BN;
  constexpr int NX = BN / TN;
  const int tx = tid % NX, ty = tid / NX;
  float acc[TM][TN] = {};
  const int klo = blockIdx.z * kchunk;
  const int khi = min(klo + kchunk, K);

  constexpr int AIT = BM * BK / 4 / 256;
  constexpr int BIT = BK * BN / 4 / 256;
  float4 pa[AIT], pb[BIT];

  auto load_tile = [&](int k0) {
#pragma unroll
    for (int it = 0; it < AIT; ++it) {
      const int s = it * 256 + tid;
      const int row = s >> 2, kq = (s & 3) << 2;
      float4 av = make_float4(0.f, 0.f, 0.f, 0.f);
      const int gr = row0 + row, gk = k0 + kq;
      if (gr < Nr) {
        const float* Ap = A + (size_t)gr * lda + gk;
        if (gk + 3 < khi) { av.x = Ap[0]; av.y = Ap[1]; av.z = Ap[2]; av.w = Ap[3]; }
        else {
          if (gk     < khi) av.x = Ap[0];
          if (gk + 1 < khi) av.y = Ap[1];
          if (gk + 2 < khi) av.z = Ap[2];
        }
      }
      pa[it] = av;
    }
#pragma unroll
    for (int it = 0; it < BIT; ++it) {
      const int s = it * 256 + tid;
      const int kr = s / (BN / 4), c = (s % (BN / 4)) << 2;
      float4 bv = make_float4(0.f, 0.f, 0.f, 0.f);
      const int gk = k0 + kr, gc = col0 + c;
      if (gk < khi) {
        const float* Bp = B + (size_t)gk * ldb + gc;
        if (gc + 3 < M) { bv.x = Bp[0]; bv.y = Bp[1]; bv.z = Bp[2]; bv.w = Bp[3]; }
        else {
          if (gc     < M) bv.x = Bp[0];
          if (gc + 1 < M) bv.y = Bp[1];
          if (gc + 2 < M) bv.z = Bp[2];
        }
      }
      pb[it] = bv;
    }
  };

  load_tile(klo);
  for (int k0 = klo; k0 < khi; k0 += BK) {
#pragma unroll
    for (int it = 0; it < AIT; ++it) {
      const int s = it * 256 + tid;
      const int row = s >> 2, kq = (s & 3) << 2;
      As[kq    ][row] = pa[it].x;
      As[kq + 1][row] = pa[it].y;
      As[kq + 2][row] = pa[it].z;
      As[kq + 3][row] = pa[it].w;
    }
#pragma unroll
    for (int it = 0; it < BIT; ++it) {
      const int s = it * 256 + tid;
      const int kr = s / (BN / 4), c = (s % (BN / 4)) << 2;
      *(float4*)&Bs[kr][c] = pb[it];
    }
    __syncthreads();
    if (k0 + BK < khi) load_tile(k0 + BK);  // overlap next-tile fetch with compute
#pragma unroll
    for (int kk = 0; kk < BK; ++kk) {
      float ar[TM], br[TN];
#pragma unroll
      for (int i = 0; i < TM; i += 4)
        *(float4*)&ar[i] = *(const float4*)&As[kk][ty * TM + i];
      if constexpr (TN == 8) {
        *(float4*)&br[0] = *(const float4*)&Bs[kk][tx * 4];
        *(float4*)&br[4] = *(const float4*)&Bs[kk][BN / 2 + tx * 4];
      } else {
        *(float4*)&br[0] = *(const float4*)&Bs[kk][tx * TN];
      }
#pragma unroll
      for (int i = 0; i < TM; ++i)
#pragma unroll
        for (int j = 0; j < TN; ++j)
          acc[i][j] += ar[i] * br[j];
    }
    __syncthreads();
  }

  float* Cz = C + (size_t)blockIdx.z * zstride;
#pragma unroll
  for (int i = 0; i < TM; ++i) {
    const int r = row0 + ty * TM + i;
    if (r >= Nr) continue;
    float* Crow = Cz + (size_t)r * ldc;
#pragma unroll
    for (int g = 0; g < TN / 4; ++g) {
      const int c = col0 + (TN == 8 ? g * (BN / 2) : 0) + tx * 4;
      if (c + 3 < M) {
        float4 v;
        v.x = acc[i][g * 4 + 0]; v.y = acc[i][g * 4 + 1];
        v.z = acc[i][g * 4 + 2]; v.w = acc[i][g * 4 + 3];
        if (bias) { v.x += bias[c]; v.y += bias[c + 1]; v.z += bias[c + 2]; v.w += bias[c + 3]; }
        if (do_relu) {
          v.x = fmaxf(v.x, 0.f); v.y = fmaxf(v.y, 0.f);
          v.z = fmaxf(v.z, 0.f); v.w = fmaxf(v.w, 0.f);
        }
        *(float4*)&Crow[c] = v;
      } else {
#pragma unroll
        for (int j = 0; j < 4; ++j) {
          if (c + j >= M) continue;
          float v = acc[i][g * 4 + j];
          if (bias) v += bias[c + j];
          if (do_relu) v = fmaxf(v, 0.f);
          Crow[c + j] = v;
        }
      }
    }
  }
}

// sum Sz split-K partials + bias (+relu), write with ldd
__global__ void bias_sum_kernel(const float* __restrict__ src, int zs, int Sz,
                                float* __restrict__ dst, int ldd,
                                const float* __restrict__ bias,
                                int Nr, int M, int do_relu) {
  int idx = blockIdx.x * blockDim.x + threadIdx.x;
  if (idx >= Nr * M) return;
  int r = idx / M, c = idx - r * M;
  float v = bias[c];
  for (int z = 0; z < Sz; ++z) v += src[idx + (size_t)z * zs];
  if (do_relu) v = fmaxf(v, 0.f);
  dst[(size_t)r * ldd + c] = v;
}

// src(512x128): rows 0..255 branch0, 256..511 branch1 -> dst[256][512] cols 0..255
__global__ void cat_kernel(const float* __restrict__ src, float* __restrict__ dst) {
  int idx = blockIdx.x * blockDim.x + threadIdx.x;
  if (idx >= 512 * 128) return;
  int r = idx >> 7, c = idx & 127;
  dst[(size_t)(r & 255) * 512 + ((r >> 8) << 7) + c] = src[idx];
}

// ------------------------- graph prep -------------------------
__global__ void hist2_kernel(const int* __restrict__ e1, const int* __restrict__ e2,
                             int* __restrict__ cnt, int E, int npass) {
  int e = blockIdx.x * blockDim.x + threadIdx.x;
  if (e < E) atomicAdd(&cnt[e1[E + e]], 1);
  else if (e < npass * E) atomicAdd(&cnt[N_NODES + e2[E + e - E]], 1);
}

// ---- 3-phase parallel exclusive scan over cnt (replaces 1-block serial scan) ----
// phase 1: each 1024-thread block scans 1024 contiguous counts (coalesced),
// writes local exclusive prefix to row_ptr and its block total to part[].
__launch_bounds__(1024)
__global__ void scan1_kernel(const int* __restrict__ cnt, int* __restrict__ row_ptr,
                             int* __restrict__ part, int n) {
  __shared__ int sh[1024];
  const int tid = threadIdx.x;
  const int i = blockIdx.x * 1024 + tid;
  const int v = (i < n) ? cnt[i] : 0;
  sh[tid] = v;
  __syncthreads();
#pragma unroll
  for (int off = 1; off < 1024; off <<= 1) {
    int t = (tid >= off) ? sh[tid - off] : 0;
    __syncthreads();
    sh[tid] += t;
    __syncthreads();
  }
  if (i < n) row_ptr[i] = sh[tid] - v;  // exclusive
  if (tid == 1023) part[blockIdx.x] = sh[tid];
}

// phase 2: exclusive scan of block totals (nb <= 40: serial on one lane is fine)
__global__ void scan2_kernel(int* __restrict__ part, int nb) {
  if (threadIdx.x == 0 && blockIdx.x == 0) {
    int run = 0;
    for (int b = 0; b < nb; ++b) { int t = part[b]; part[b] = run; run += t; }
  }
}

// phase 3: add block offsets, init cursor, compute dinv, write total
__global__ void scan3_kernel(const int* __restrict__ cnt, int* __restrict__ row_ptr,
                             const int* __restrict__ part, int* __restrict__ cursor,
                             float* __restrict__ dinv, int n, int total) {
  int i = blockIdx.x * blockDim.x + threadIdx.x;
  if (i >= n) return;
  int rp = row_ptr[i] + part[i >> 10];
  row_ptr[i] = rp;
  cursor[i] = rp;
  dinv[i] = rsqrtf((float)(cnt[i] + 1));
  if (i == 0) row_ptr[n] = total;
}

__global__ void scatter2_kernel(const int* __restrict__ e1, const int* __restrict__ e2,
                                int* __restrict__ cursor, int* __restrict__ col_idx,
                                int E, int npass) {
  int e = blockIdx.x * blockDim.x + threadIdx.x;
  if (e < E) {
    int p = atomicAdd(&cursor[e1[E + e]], 1);
    col_idx[p] = e1[e];
  } else if (e < npass * E) {
    int j = e - E;
    int p = atomicAdd(&cursor[N_NODES + e2[E + j]], 1);
    col_idx[p] = N_NODES + e2[j];
  }
}

// ------------------------- normalized aggregation: out = D^-1/2 (A+I) D^-1/2 x ---------
__global__ void aggf2_kernel(const float* __restrict__ h, const float* __restrict__ h2,
                             int nsplit, const int* __restrict__ row_ptr,
                             const int* __restrict__ col_idx, const float* __restrict__ dinv,
                             float* __restrict__ out, int F) {
  const int n = blockIdx.x;
  const int v = threadIdx.x;
  const bool ok = v < (F >> 1);
  const float din = dinv[n];
  auto rowp = [&](int s) -> const float2* {
    const float* base = (s < nsplit) ? h + (size_t)s * F : h2 + (size_t)(s - nsplit) * F;
    return (const float2*)base;
  };
  float2 a = make_float2(0.f, 0.f);
  if (ok) { float2 x = rowp(n)[v]; a.x = din * x.x; a.y = din * x.y; }
  const int beg = row_ptr[n], end = row_ptr[n + 1];
  int e = beg;
  for (; e + 1 < end; e += 2) {
    int s0 = col_idx[e], s1 = col_idx[e + 1];
    float d0 = dinv[s0], d1 = dinv[s1];
    if (ok) {
      float2 x0 = rowp(s0)[v], x1 = rowp(s1)[v];
      a.x += d0 * x0.x + d1 * x1.x;
      a.y += d0 * x0.y + d1 * x1.y;
    }
  }
  if (e < end) {
    int s0 = col_idx[e];
    float d0 = dinv[s0];
    if (ok) { float2 x0 = rowp(s0)[v]; a.x += d0 * x0.x; a.y += d0 * x0.y; }
  }
  if (ok) {
    float2 o; o.x = din * a.x; o.y = din * a.y;
    ((float2*)(out + (size_t)n * F))[v] = o;
  }
}

__global__ void aggf4_kernel(const float* __restrict__ h, const int* __restrict__ row_ptr,
                             const int* __restrict__ col_idx, const float* __restrict__ dinv,
                             float* __restrict__ out, int F) {
  const int n = blockIdx.x;
  const int v = threadIdx.x;
  const bool ok = v < (F >> 2);
  const float din = dinv[n];
  const float4* hv = (const float4*)h;
  const int vs = F >> 2;
  float4 a = make_float4(0.f, 0.f, 0.f, 0.f);
  if (ok) {
    float4 x = hv[(size_t)n * vs + v];
    a.x = din * x.x; a.y = din * x.y; a.z = din * x.z; a.w = din * x.w;
  }
  const int beg = row_ptr[n], end = row_ptr[n + 1];
  int e = beg;
  for (; e + 1 < end; e += 2) {
    int s0 = col_idx[e], s1 = col_idx[e + 1];
    float d0 = dinv[s0], d1 = dinv[s1];
    if (ok) {
      float4 x0 = hv[(size_t)s0 * vs + v], x1 = hv[(size_t)s1 * vs + v];
      a.x += d0 * x0.x + d1 * x1.x;
      a.y += d0 * x0.y + d1 * x1.y;
      a.z += d0 * x0.z + d1 * x1.z;
      a.w += d0 * x0.w + d1 * x1.w;
    }
  }
  if (e < end) {
    int s0 = col_idx[e];
    float d0 = dinv[s0];
    if (ok) {
      float4 x0 = hv[(size_t)s0 * vs + v];
      a.x += d0 * x0.x; a.y += d0 * x0.y; a.z += d0 * x0.z; a.w += d0 * x0.w;
    }
  }
  if (ok) {
    float4 o;
    o.x = din * a.x; o.y = din * a.y; o.z = din * a.z; o.w = din * a.w;
    ((float4*)(out + (size_t)n * F))[v] = o;
  }
}

__global__ void starts2_kernel(const int* __restrict__ b1, const int* __restrict__ b2,
                               int* __restrict__ s1, int* __restrict__ s2, int n, int npass) {
  int i = blockIdx.x * blockDim.x + threadIdx.x;
  if (i < n) {
    if (i == 0) { s1[0] = 0; s1[N_GRAPH] = n; }
    else if (b1[i] != b1[i - 1]) s1[b1[i]] = i;
  } else if (i < npass * n) {
    int j = i - n;
    if (j == 0) { s2[0] = n; s2[N_GRAPH] = 2 * n; }
    else if (b2[j] != b2[j - 1]) s2[b2[j]] = n + j;
  }
}

__global__ void pool_kernel(const float* __restrict__ x, const int* __restrict__ s1,
                            const int* __restrict__ s2, float* __restrict__ pooled,
                            int F, int pool_base) {
  int g = blockIdx.x;
  const int* st = (g < N_GRAPH) ? s1 : s2;
  int gi = g & (N_GRAPH - 1);
  int beg = st[gi], end = st[gi + 1];
  for (int f = threadIdx.x; f < F; f += blockDim.x) {
    float m = 0.f;  // post-ReLU inputs >= 0
    for (int nn = beg; nn < end; ++nn) m = fmaxf(m, x[(size_t)nn * F + f]);
    pooled[(size_t)(pool_base + g) * F + f] = m;
  }
}

__global__ void rownorm_kernel(const float* __restrict__ cell, float* __restrict__ cv, int F) {
  int g = blockIdx.x;
  __shared__ float red[256];
  int tid = threadIdx.x;
  const float* row = cell + (size_t)g * F;
  float s = 0.f;
  for (int f = tid; f < F; f += 256) { float v = row[f]; s += v * v; }
  red[tid] = s;
  __syncthreads();
  for (int off = 128; off > 0; off >>= 1) {
    if (tid < off) red[tid] += red[tid + off];
    __syncthreads();
  }
  float inv = 1.f / fmaxf(sqrtf(red[0]), 1e-12f);
  float* orow = cv + (size_t)g * F;
  for (int f = tid; f < F; f += 256) orow[f] = row[f] * inv;
}

// ------------------------- launcher -------------------------
extern "C" void kernel_launch(void* const* d_in, const int* in_sizes, int n_in,
                              void* d_out, int out_size, void* d_ws, size_t ws_size,
                              hipStream_t stream) {
  (void)in_sizes; (void)n_in; (void)out_size;
  const float* x1  = (const float*)d_in[0];
  const int*   ei1 = (const int*)d_in[1];
  const int*   bt1 = (const int*)d_in[2];
  const float* x2  = (const float*)d_in[3];
  const int*   ei2 = (const int*)d_in[4];
  const int*   bt2 = (const int*)d_in[5];
  const float* cell = (const float*)d_in[6];
  const float* Wc1 = (const float*)d_in[7];  const float* bc1 = (const float*)d_in[8];
  const float* Wc2 = (const float*)d_in[9];  const float* bc2 = (const float*)d_in[10];
  const float* Wc3 = (const float*)d_in[11]; const float* bc3 = (const float*)d_in[12];
  const float* Wg1 = (const float*)d_in[13]; const float* bg1 = (const float*)d_in[14];
  const float* Wg2 = (const float*)d_in[15]; const float* bg2 = (const float*)d_in[16];
  const float* Wr1 = (const float*)d_in[17]; const float* br1 = (const float*)d_in[18];
  const float* Wr2 = (const float*)d_in[19]; const float* br2 = (const float*)d_in[20];
  const float* Wr3 = (const float*)d_in[21]; const float* br3 = (const float*)d_in[22];
  const float* Wf1 = (const float*)d_in[23]; const float* bf1 = (const float*)d_in[24];
  const float* Wf2 = (const float*)d_in[25]; const float* bf2 = (const float*)d_in[26];
  const float* Wf3 = (const float*)d_in[27]; const float* bf3 = (const float*)d_in[28];
  const float* Wo  = (const float*)d_in[29]; const float* bo  = (const float*)d_in[30];
  float* out = (float*)d_out;

  const bool batched = ws_size >= (size_t)95 * 1024 * 1024;
  const int NPASS = batched ? 2 : 1;
  const int NN = NPASS * N_NODES;

  char* ws = (char*)d_ws;
  size_t off = 0;
  auto alloc_f = [&](size_t ne) { float* p = (float*)(ws + off); off += ne * 4; return p; };
  auto alloc_i = [&](size_t ne) { int* p = (int*)(ws + off); off += ne * 4; return p; };
  float* xbuf   = alloc_f((size_t)NN * 312);   // activations; also aliased as split-K acc
  float* abuf   = alloc_f((size_t)NN * 156);
  float* dinv   = alloc_f(NN);
  float* pooled = alloc_f((size_t)512 * 312);
  float* cvbuf  = alloc_f((size_t)N_GRAPH * 954);
  float* gtmp1  = alloc_f((size_t)512 * 2048);
  float* gtmp2  = alloc_f((size_t)512 * 512);
  float* gtmp3  = alloc_f((size_t)N_GRAPH * 256);
  float* catbuf = alloc_f((size_t)N_GRAPH * 512);
  int* cnt     = alloc_i(NN);
  int* row_ptr = alloc_i(NN + 1);
  int* cursor  = alloc_i(NN);
  int* col_idx = alloc_i(NPASS * N_EDGES);
  int* part    = alloc_i(64);
  int* start1  = alloc_i(N_GRAPH + 1);
  int* start2  = alloc_i(N_GRAPH + 1);
  float* accb  = xbuf;  // split-K partials (MLP runs after pooling; xbuf free then)

  auto gemm_big = [&](const float* A, int lda, const float* B, int ldb, float* C, int ldc,
                      const float* bias, int Nr, int K, int M, int relu) {
    dim3 grid((M + 127) / 128, (Nr + 127) / 128, 1);
    gemm_t<128, 128, 8, 8><<<grid, 256, 0, stream>>>(A, lda, B, ldb, C, ldc, 0, bias,
                                                     Nr, K, M, relu, K);
  };
  auto gemm_med = [&](const float* A, int lda, const float* B, int ldb, float* C, int ldc,
                      const float* bias, int Nr, int K, int M, int relu) {
    dim3 grid((M + 63) / 64, (Nr + 127) / 128, 1);
    gemm_t<128, 64, 8, 4><<<grid, 256, 0, stream>>>(A, lda, B, ldb, C, ldc, 0, bias,
                                                    Nr, K, M, relu, K);
  };
  auto gemm_small = [&](const float* A, int lda, const float* B, int ldb, float* C, int ldc,
                        const float* bias, int Nr, int K, int M, int relu) {
    dim3 grid((M + 63) / 64, (Nr + 63) / 64, 1);
    gemm_t<64, 64, 4, 4><<<grid, 256, 0, stream>>>(A, lda, B, ldb, C, ldc, 0, bias,
                                                   Nr, K, M, relu, K);
  };
  // split-K MLP layer (Nr = 256): partial stores per z-slice + summing bias/act pass
  auto splitk = [&](const float* A, int lda, const float* B, int M_, int K_, int S,
                    const float* bias, float* dst, int ldd, int relu) {
    int kchunk = (((K_ + S - 1) / S) + 15) / 16 * 16;
    int Sz = (K_ + kchunk - 1) / kchunk;
    dim3 grid((M_ + 63) / 64, (N_GRAPH + 63) / 64, Sz);
    gemm_t<64, 64, 4, 4><<<grid, 256, 0, stream>>>(A, lda, B, M_, accb, M_, N_GRAPH * M_,
                                                   nullptr, N_GRAPH, K_, M_, 0, kchunk);
    int tot = N_GRAPH * M_;
    bias_sum_kernel<<<(tot + 255) / 256, 256, 0, stream>>>(accb, N_GRAPH * M_, Sz, dst, ldd,
                                                           bias, N_GRAPH, M_, relu);
  };

  auto drug_pass = [&](const float* xa, const float* xb, const int* eia, const int* eib,
                       const int* bta, const int* btb, int npass, int pool_base) {
    const int nn = npass * N_NODES;
    const int te = npass * N_EDGES;
    const int nb = (nn + 1023) / 1024;
    hipMemsetAsync(cnt, 0, nn * sizeof(int), stream);
    hist2_kernel<<<(te + 255) / 256, 256, 0, stream>>>(eia, eib, cnt, N_EDGES, npass);
    scan1_kernel<<<nb, 1024, 0, stream>>>(cnt, row_ptr, part, nn);
    scan2_kernel<<<1, 64, 0, stream>>>(part, nb);
    scan3_kernel<<<(nn + 255) / 256, 256, 0, stream>>>(cnt, row_ptr, part, cursor, dinv, nn, te);
    scatter2_kernel<<<(te + 255) / 256, 256, 0, stream>>>(eia, eib, cursor, col_idx, N_EDGES, npass);
    // layer 1: agg(78, dual-source virtual concat) -> GEMM 78->78 (+bias,relu)
    aggf2_kernel<<<nn, 64, 0, stream>>>(xa, xb, N_NODES, row_ptr, col_idx, dinv, abuf, 78);
    gemm_med(abuf, 78, Wc1, 78, xbuf, 78, bc1, nn, 78, 78, 1);
    // layer 2: agg(78) -> GEMM 78->156
    aggf2_kernel<<<nn, 64, 0, stream>>>(xbuf, xbuf, nn, row_ptr, col_idx, dinv, abuf, 78);
    gemm_med(abuf, 78, Wc2, 156, xbuf, 156, bc2, nn, 78, 156, 1);
    // layer 3: agg(156) -> GEMM 156->312
    aggf4_kernel<<<nn, 64, 0, stream>>>(xbuf, row_ptr, col_idx, dinv, abuf, 156);
    gemm_big(abuf, 156, Wc3, 312, xbuf, 312, bc3, nn, 156, 312, 1);
    // pool
    starts2_kernel<<<(nn + 255) / 256, 256, 0, stream>>>(bta, btb, start1, start2, N_NODES, npass);
    pool_kernel<<<npass * N_GRAPH, 128, 0, stream>>>(xbuf, start1, start2, pooled, 312, pool_base);
  };

  if (batched) {
    drug_pass(x1, x2, ei1, ei2, bt1, bt2, 2, 0);
  } else {
    drug_pass(x1, x1, ei1, ei1, bt1, bt1, 1, 0);
    drug_pass(x2, x2, ei2, ei2, bt2, bt2, 1, N_GRAPH);
  }

  // drug head on both branches at once (512 rows; shared weights)
  gemm_med(pooled, 312, Wg1, 156, gtmp1, 156, bg1, 2 * N_GRAPH, 312, 156, 1);
  gemm_med(gtmp1, 156, Wg2, 128, gtmp2, 128, bg2, 2 * N_GRAPH, 156, 128, 0);
  cat_kernel<<<(512 * 128 + 255) / 256, 256, 0, stream>>>(gtmp2, catbuf);

  // cell branch + head MLP (256-row deep-K layers via split-K)
  rownorm_kernel<<<N_GRAPH, 256, 0, stream>>>(cell, cvbuf, 954);
  splitk(cvbuf, 954, Wr1, 2048, 954, 4,   br1, gtmp1, 2048, 1);
  splitk(gtmp1, 2048, Wr2, 512, 2048, 16, br2, gtmp2, 512, 1);
  splitk(gtmp2, 512, Wr3, 256, 512, 8,    br3, catbuf + 256, 512, 1);
  splitk(catbuf, 512, Wf1, 1024, 512, 8,  bf1, gtmp1, 1024, 1);
  splitk(gtmp1, 1024, Wf2, 512, 1024, 16, bf2, gtmp2, 512, 1);
  splitk(gtmp2, 512, Wf3, 128, 512, 16,   bf3, gtmp3, 128, 1);
  gemm_small(gtmp3, 128, Wo, 2, out, 2, bo, N_GRAPH, 128, 2, 0);
}